// Round 2
// baseline (215.317 us; speedup 1.0000x reference)
//
#include <hip/hip_runtime.h>
#include <stdint.h>

typedef float  f32x4  __attribute__((ext_vector_type(4)));
typedef float  f32x16 __attribute__((ext_vector_type(16)));
typedef short  s16x8  __attribute__((ext_vector_type(8)));
typedef unsigned short u16x4 __attribute__((ext_vector_type(4)));

#define LPAD 2052   // L + 4 padded positions per batch row

__device__ __forceinline__ float bf2f(unsigned short u){
  unsigned v = ((unsigned)u) << 16;
  return __builtin_bit_cast(float, v);
}
__device__ __forceinline__ unsigned short f2bf(float f){
  unsigned u = __builtin_bit_cast(unsigned, f);
  u += 0x7fffu + ((u >> 16) & 1u);
  return (unsigned short)(u >> 16);
}
__device__ __forceinline__ unsigned cvt_pk_bf16(float lo, float hi){
  unsigned r;
  asm volatile("v_cvt_pk_bf16_f32 %0, %1, %2" : "=v"(r) : "v"(lo), "v"(hi));
  return r;
}

// ---------------- K0: fp32 -> bf16 convert (vectorized) ----------------
__global__ void k_cvt(const float* __restrict__ src, unsigned short* __restrict__ dst, int n4){
  int i = blockIdx.x * 256 + threadIdx.x;
  if (i >= n4) return;
  f32x4 v = ((const f32x4*)src)[i];
  u16x4 o;
  o[0] = f2bf(v[0]); o[1] = f2bf(v[1]); o[2] = f2bf(v[2]); o[3] = f2bf(v[3]);
  ((u16x4*)dst)[i] = o;
}

// ---------------- K0b: write identity pad matrices ----------------
__global__ void k_eye(unsigned short* __restrict__ H){
  int t = blockIdx.x * 256 + threadIdx.x;       // B*4*1024 = 32768
  int b = t >> 12;
  int r = t & 4095;
  int which = r >> 10;                           // 0..3
  int ij = r & 1023;
  int p = (which < 2) ? which : (2048 + which);  // 0,1,2050,2051
  H[((size_t)(b * LPAD + p) << 10) + ij] = ((ij >> 5) == (ij & 31)) ? 0x3F80 : 0;
}

// ---------------- K_fuseW: V[g][fk] = sum_e Wd[e][g]*Wa[f][e*5+k] (bf16, rows 1024+fk of B)
//                  + cpart[fk] = sum_e bd[e]*Wa[f][e*5+k]
//                  + eyepart[fk] = sum_i Wa[f][(i*33)*5+k] ----------------
__global__ __launch_bounds__(256) void k_fuseW(const float* __restrict__ Wd,
                                               const float* __restrict__ Wa,
                                               const float* __restrict__ bd,
                                               unsigned short* __restrict__ Wbf,
                                               float* __restrict__ cpart,
                                               float* __restrict__ eyepart){
  __shared__ unsigned char smem[53248];
  unsigned short* wal = (unsigned short*)smem;   // [1024][26] bf16
  const int tid = threadIdx.x;
  for (int i = tid; i < 25600; i += 256){
    int e = i / 25, fk = i - e * 25;
    int f = fk / 5, k = fk - 5 * f;
    wal[e * 26 + fk] = f2bf(Wa[f * 5120 + e * 5 + k]);
  }
  __syncthreads();
  const int gl = tid & 31, ch = tid >> 5;
  const int g = blockIdx.x * 32 + gl;
  float acc[25];
  #pragma unroll
  for (int fk = 0; fk < 25; fk++) acc[fk] = 0.f;
  for (int e = ch * 128; e < ch * 128 + 128; ++e){
    float wd = Wd[(size_t)e * 1024 + g];
    #pragma unroll
    for (int fk = 0; fk < 25; fk++) acc[fk] += wd * bf2f(wal[e * 26 + fk]);
  }
  __syncthreads();
  float* red = (float*)smem;                     // [8][32][25] fp32 (reuses smem)
  #pragma unroll
  for (int fk = 0; fk < 25; fk++) red[(ch * 32 + gl) * 25 + fk] = acc[fk];
  __syncthreads();
  for (int i = tid; i < 800; i += 256){
    int g2 = i / 25, fk = i - g2 * 25;
    float s = 0.f;
    #pragma unroll
    for (int c = 0; c < 8; c++) s += red[(c * 32 + g2) * 25 + fk];
    Wbf[(size_t)(1024 + fk) * 1024 + blockIdx.x * 32 + g2] = f2bf(s);
  }
  for (int i = tid; i < 224; i += 256){          // zero pad rows fk=25..31
    int fk = 25 + i / 32, g2 = i & 31;
    Wbf[(size_t)(1024 + fk) * 1024 + blockIdx.x * 32 + g2] = 0;
  }
  if (blockIdx.x == 0){
    if (tid < 25){
      int f = tid / 5, k = tid - 5 * f;
      float s = 0.f;
      #pragma unroll
      for (int i2 = 0; i2 < 32; i2++) s += Wa[f * 5120 + i2 * 165 + k];
      eyepart[tid] = s;
    } else if (tid >= 64 && tid < 89){
      int fk = tid - 64, f = fk / 5, k = fk - 5 * f;
      float s = 0.f;
      for (int e = 0; e < 1024; e++) s += bd[e] * Wa[f * 5120 + e * 5 + k];
      cpart[fk] = s;
    }
  }
}

// ---------------- K1: h = X*W^T + bias (bn<8) AND part = X*V (bn==8) ----------------
__global__ __launch_bounds__(256) void k_gemm(const unsigned short* __restrict__ A,   // [16384][1024] bf16
                                              const unsigned short* __restrict__ Bw,  // [1152][1024] bf16
                                              const float* __restrict__ bias,
                                              unsigned short* __restrict__ H,         // [B*2052][1024] bf16
                                              float* __restrict__ part){              // [16384][25] fp32
  __shared__ unsigned short sA[128 * 32];
  __shared__ unsigned short sB[128 * 32];
  const int tid = threadIdx.x;
  const int w = tid >> 6, l = tid & 63;
  const int bn = blockIdx.x, bm = blockIdx.y;    // bn fastest: 9 blocks share A tile
  const int M0 = bm * 128, N0 = bn * 128;
  const int wm = (w >> 1) * 64, wn = (w & 1) * 64;
  const int lm = l & 15, lk = l >> 4;
  f32x4 acc[4][4] = {};

  for (int kk = 0; kk < 1024; kk += 32){
    #pragma unroll
    for (int t = 0; t < 2; t++){
      int c = t * 256 + tid;
      const unsigned short* ga = A  + (size_t)(M0 + (c >> 2)) * 1024 + (kk + ((c & 3) << 3));
      __builtin_amdgcn_global_load_lds((const __attribute__((address_space(1))) void*)ga,
                                       (__attribute__((address_space(3))) void*)&sA[(t * 256 + w * 64) * 8],
                                       16, 0, 0);
      const unsigned short* gb = Bw + (size_t)(N0 + (c >> 2)) * 1024 + (kk + ((c & 3) << 3));
      __builtin_amdgcn_global_load_lds((const __attribute__((address_space(1))) void*)gb,
                                       (__attribute__((address_space(3))) void*)&sB[(t * 256 + w * 64) * 8],
                                       16, 0, 0);
    }
    __syncthreads();
    s16x8 aF[4], bF[4];
    #pragma unroll
    for (int m = 0; m < 4; m++) aF[m] = *(const s16x8*)&sA[(wm + m * 16 + lm) * 32 + lk * 8];
    #pragma unroll
    for (int n = 0; n < 4; n++) bF[n] = *(const s16x8*)&sB[(wn + n * 16 + lm) * 32 + lk * 8];
    #pragma unroll
    for (int m = 0; m < 4; m++){
      #pragma unroll
      for (int n = 0; n < 4; n++){
        acc[m][n] = __builtin_amdgcn_mfma_f32_16x16x32_bf16(aF[m], bF[n], acc[m][n], 0, 0, 0);
      }
    }
    __syncthreads();
  }

  if (bn < 8){
    float bv[4];
    #pragma unroll
    for (int n = 0; n < 4; n++) bv[n] = bias[N0 + wn + n * 16 + lm];
    #pragma unroll
    for (int m = 0; m < 4; m++){
      #pragma unroll
      for (int r = 0; r < 4; r++){
        int gm = M0 + wm + m * 16 + lk * 4 + r;
        int bb = gm >> 11, li = gm & 2047;
        unsigned short* orow = H + ((size_t)(bb * LPAD + 2 + li) << 10);
        #pragma unroll
        for (int n = 0; n < 4; n++){
          orow[N0 + wn + n * 16 + lm] = f2bf(acc[m][n][r] + bv[n]);
        }
      }
    }
  } else {
    if (wn == 0){
      #pragma unroll
      for (int m = 0; m < 4; m++){
        #pragma unroll
        for (int r = 0; r < 4; r++){
          int gm = M0 + wm + m * 16 + lk * 4 + r;
          float* prow = part + (size_t)gm * 25;
          #pragma unroll
          for (int n = 0; n < 2; n++){
            int fk = n * 16 + lm;
            if (fk < 25) prow[fk] = acc[m][n][r];
          }
        }
      }
    }
  }
}

// ---------------- K3: scores -> leaky_relu -> softmax -> s = prod(alpha) ----------------
__global__ void k_alpha(const float* __restrict__ part, const float* __restrict__ battn,
                        const float* __restrict__ cpart, const float* __restrict__ eyepart,
                        float* __restrict__ sprod){
  int t = blockIdx.x * 256 + threadIdx.x;
  if (t >= 16384) return;
  int bb = t >> 11, li = t & 2047;
  float sc[5];
  #pragma unroll
  for (int f = 0; f < 5; f++){
    float a = battn[f];
    #pragma unroll
    for (int k = 0; k < 5; k++){
      int q = li + k;
      int fk = f * 5 + k;
      if (q >= 2 && q < 2050)
        a += part[((size_t)(bb << 11) + (q - 2)) * 25 + fk] + cpart[fk];
      else
        a += eyepart[fk];
    }
    sc[f] = (a > 0.f) ? a : 0.01f * a;
  }
  float m = sc[0];
  #pragma unroll
  for (int f = 1; f < 5; f++) m = fmaxf(m, sc[f]);
  float e0 = expf(sc[0] - m), e1 = expf(sc[1] - m), e2 = expf(sc[2] - m),
        e3 = expf(sc[3] - m), e4 = expf(sc[4] - m);
  float ssum = e0 + e1 + e2 + e3 + e4;
  float inv = 1.f / ssum;
  float inv2 = inv * inv;
  sprod[t] = (e0 * e1 * e2 * e3 * e4) * inv2 * inv2 * inv;
}

// ---------------- K4: per-position 32x32 matrix chain (MFMA), scaled by s ----------------
__global__ __launch_bounds__(256) void k_chain(const unsigned short* __restrict__ H,
                                               const float* __restrict__ sp,
                                               float* __restrict__ out){
  const int tid = threadIdx.x;
  const int w = tid >> 6, l = tid & 63;
  const int pos = blockIdx.x * 4 + w;
  const int bb = pos >> 11, li = pos & 2047;
  const unsigned short* hbase = H + ((size_t)(bb * LPAD + li) << 10);
  const int col = l & 31;
  const int kh = (l >> 5) << 3;   // 0 or 8

  // initial carried matrix M = h4, loaded directly as B-fragments (col-major access)
  const unsigned short* h4 = hbase + 4 * 1024;
  unsigned q0, q1, q2, q3, q4, q5, q6, q7;
  {
    #define LD2(kk) ((unsigned)h4[(kk) * 32 + col] | ((unsigned)h4[((kk) + 1) * 32 + col] << 16))
    q0 = LD2(kh + 0);  q1 = LD2(kh + 2);  q2 = LD2(kh + 4);  q3 = LD2(kh + 6);
    q4 = LD2(kh + 16); q5 = LD2(kh + 18); q6 = LD2(kh + 20); q7 = LD2(kh + 22);
    #undef LD2
  }
  union { unsigned u[4]; s16x8 v; } ub0, ub1;
  ub0.u[0] = q0; ub0.u[1] = q1; ub0.u[2] = q2; ub0.u[3] = q3;
  ub1.u[0] = q4; ub1.u[1] = q5; ub1.u[2] = q6; ub1.u[3] = q7;
  s16x8 Bf0 = ub0.v, Bf1 = ub1.v;

  f32x16 acc;
  #pragma unroll
  for (int st = 0; st < 4; st++){
    const int km = 3 - st;                       // M = h_km * M
    const unsigned short* hA = hbase + (km << 10);
    s16x8 A0 = *(const s16x8*)(hA + col * 32 + kh);
    s16x8 A1 = *(const s16x8*)(hA + col * 32 + kh + 16);
    f32x16 z = {0,0,0,0,0,0,0,0,0,0,0,0,0,0,0,0};
    acc = __builtin_amdgcn_mfma_f32_32x32x16_bf16(A0, Bf0, z,   0, 0, 0);
    acc = __builtin_amdgcn_mfma_f32_32x32x16_bf16(A1, Bf1, acc, 0, 0, 0);
    if (st < 3){
      unsigned d0 = cvt_pk_bf16(acc[0],  acc[1]);
      unsigned d1 = cvt_pk_bf16(acc[2],  acc[3]);
      unsigned d2 = cvt_pk_bf16(acc[4],  acc[5]);
      unsigned d3 = cvt_pk_bf16(acc[6],  acc[7]);
      unsigned d4 = cvt_pk_bf16(acc[8],  acc[9]);
      unsigned d5 = cvt_pk_bf16(acc[10], acc[11]);
      unsigned d6 = cvt_pk_bf16(acc[12], acc[13]);
      unsigned d7 = cvt_pk_bf16(acc[14], acc[15]);
      unsigned p0 = __shfl_xor(d0, 32, 64);
      unsigned p1 = __shfl_xor(d1, 32, 64);
      unsigned p2 = __shfl_xor(d2, 32, 64);
      unsigned p3 = __shfl_xor(d3, 32, 64);
      unsigned p4 = __shfl_xor(d4, 32, 64);
      unsigned p5 = __shfl_xor(d5, 32, 64);
      unsigned p6 = __shfl_xor(d6, 32, 64);
      unsigned p7 = __shfl_xor(d7, 32, 64);
      const bool lo = (l < 32);
      ub0.u[0] = lo ? d0 : p2;  ub0.u[1] = lo ? d1 : p3;
      ub0.u[2] = lo ? p0 : d2;  ub0.u[3] = lo ? p1 : d3;
      ub1.u[0] = lo ? d4 : p6;  ub1.u[1] = lo ? d5 : p7;
      ub1.u[2] = lo ? p4 : d6;  ub1.u[3] = lo ? p5 : d7;
      Bf0 = ub0.v; Bf1 = ub1.v;
    }
  }

  const float sv = sp[pos];
  float* ob = out + ((size_t)pos << 10);
  #pragma unroll
  for (int t = 0; t < 16; t++){
    int row = (t & 3) + 8 * (t >> 2) + ((l >> 5) << 2);
    ob[row * 32 + col] = sv * acc[t];
  }
}

// ---------------- launcher ----------------
extern "C" void kernel_launch(void* const* d_in, const int* in_sizes, int n_in,
                              void* d_out, int out_size, void* d_ws, size_t ws_size,
                              hipStream_t stream){
  const float* X  = (const float*)d_in[0];   // [8][2048][32][32]
  const float* Wd = (const float*)d_in[1];   // [1024][1024]
  const float* bd = (const float*)d_in[2];   // [1024]
  const float* Wa = (const float*)d_in[3];   // [5][5120]
  const float* ba = (const float*)d_in[4];   // [5]
  float* out = (float*)d_out;

  char* ws = (char*)d_ws;
  unsigned short* Hpad = (unsigned short*)ws;                               // 33,619,968 B
  unsigned short* Wbf  = (unsigned short*)(ws + 33619968);                  // 1152*1024*2 = 2,359,296 B
  float*          sprod= (float*)(ws + 33619968 + 2359296);                 // 65,536 B
  float*          cpart= (float*)(ws + 33619968 + 2359296 + 65536);         // 128 B
  float*          eyep = (float*)(ws + 33619968 + 2359296 + 65536 + 128);   // 128 B
  unsigned short* Xbf  = (unsigned short*)d_out;                            // 32 MiB scratch in d_out head
  float*          part = (float*)((char*)d_out + 33554432);                 // 16384*25*4 in d_out tail

  k_cvt<<<16384, 256, 0, stream>>>(X, Xbf, 4194304);
  k_cvt<<<1024, 256, 0, stream>>>(Wd, Wbf, 262144);
  k_eye<<<128, 256, 0, stream>>>(Hpad);
  k_fuseW<<<32, 256, 0, stream>>>(Wd, Wa, bd, Wbf, cpart, eyep);
  dim3 g1(9, 128);
  k_gemm<<<g1, 256, 0, stream>>>(Xbf, Wbf, bd, Hpad, part);
  k_alpha<<<64, 256, 0, stream>>>(part, ba, cpart, eyep, sprod);
  k_chain<<<4096, 256, 0, stream>>>(Hpad, sprod, out);
}

// Round 3
// 141.295 us; speedup vs baseline: 1.5239x; 1.5239x over previous
//
#include <hip/hip_runtime.h>
#include <stdint.h>

typedef float  f32x4  __attribute__((ext_vector_type(4)));
typedef float  f32x16 __attribute__((ext_vector_type(16)));
typedef short  s16x8  __attribute__((ext_vector_type(8)));
typedef unsigned short u16x4 __attribute__((ext_vector_type(4)));

#define LPAD 2052   // L + 4 padded positions per batch row

__device__ __forceinline__ float bf2f(unsigned short u){
  unsigned v = ((unsigned)u) << 16;
  return __builtin_bit_cast(float, v);
}
__device__ __forceinline__ unsigned short f2bf(float f){
  unsigned u = __builtin_bit_cast(unsigned, f);
  u += 0x7fffu + ((u >> 16) & 1u);
  return (unsigned short)(u >> 16);
}
__device__ __forceinline__ unsigned cvt_pk_bf16(float lo, float hi){
  unsigned r;
  asm volatile("v_cvt_pk_bf16_f32 %0, %1, %2" : "=v"(r) : "v"(lo), "v"(hi));
  return r;
}

// ---------------- K0: fp32 -> bf16 convert (vectorized) ----------------
__global__ void k_cvt(const float* __restrict__ src, unsigned short* __restrict__ dst, int n4){
  int i = blockIdx.x * 256 + threadIdx.x;
  if (i >= n4) return;
  f32x4 v = ((const f32x4*)src)[i];
  u16x4 o;
  o[0] = f2bf(v[0]); o[1] = f2bf(v[1]); o[2] = f2bf(v[2]); o[3] = f2bf(v[3]);
  ((u16x4*)dst)[i] = o;
}

// ---------------- K0b: write identity pad matrices ----------------
__global__ void k_eye(unsigned short* __restrict__ H){
  int t = blockIdx.x * 256 + threadIdx.x;       // B*4*1024 = 32768
  int b = t >> 12;
  int r = t & 4095;
  int which = r >> 10;                           // 0..3
  int ij = r & 1023;
  int p = (which < 2) ? which : (2048 + which);  // 0,1,2050,2051
  H[((size_t)(b * LPAD + p) << 10) + ij] = ((ij >> 5) == (ij & 31)) ? 0x3F80 : 0;
}

// ---------------- K_fuseW1: Vpart[ey][g][fk] = sum_{e in chunk ey} Wd[e][g]*Wa2[e][fk] ----------------
__global__ __launch_bounds__(256) void k_fuseW1(const float* __restrict__ Wd,
                                                const float* __restrict__ Wa,
                                                float* __restrict__ Vpart){   // [8][1024][25] fp32
  __shared__ float smem[6400];          // phase A: was2[128][26]=3328f ; phase B: red[256][25]=6400f
  float* was2 = smem;
  const int tid = threadIdx.x;
  const int gx = blockIdx.x, ey = blockIdx.y;
  for (int i = tid; i < 3200; i += 256){
    int le = i / 25, fk = i - le * 25;
    int f = fk / 5, k = fk - 5 * f;
    was2[le * 26 + fk] = Wa[f * 5120 + (ey * 128 + le) * 5 + k];
  }
  __syncthreads();
  const int gl = tid & 31, ch = tid >> 5;   // 32 g-lanes x 8 e-subchunks
  const int g = gx * 32 + gl;
  float acc[25];
  #pragma unroll
  for (int fk = 0; fk < 25; fk++) acc[fk] = 0.f;
  for (int le = ch * 16; le < ch * 16 + 16; ++le){
    float wd = Wd[(size_t)(ey * 128 + le) * 1024 + g];
    #pragma unroll
    for (int fk = 0; fk < 25; fk++) acc[fk] += wd * was2[le * 26 + fk];
  }
  __syncthreads();
  float* red = smem;                    // [256][25]
  #pragma unroll
  for (int fk = 0; fk < 25; fk++) red[tid * 25 + fk] = acc[fk];
  __syncthreads();
  for (int i = tid; i < 800; i += 256){
    int g2 = i / 25, fk = i - g2 * 25;
    float s = 0.f;
    #pragma unroll
    for (int c = 0; c < 8; c++) s += red[(c * 32 + g2) * 25 + fk];
    Vpart[((size_t)ey * 1024 + gx * 32 + g2) * 25 + fk] = s;
  }
}

// ---------------- K_fuseW2: reduce Vpart -> bf16 B-rows 1024+fk; cpart; eyepart ----------------
__global__ __launch_bounds__(256) void k_fuseW2(const float* __restrict__ Vpart,
                                                const float* __restrict__ Wa,
                                                const float* __restrict__ bd,
                                                unsigned short* __restrict__ Wbf,
                                                float* __restrict__ cpart,
                                                float* __restrict__ eyepart){
  const int tid = threadIdx.x;
  const int b = blockIdx.x;
  if (b < 100){
    int i = b * 256 + tid;
    if (i < 25600){
      int g = i / 25, fk = i - g * 25;
      float s = 0.f;
      #pragma unroll
      for (int ey = 0; ey < 8; ey++) s += Vpart[((size_t)ey * 1024 + g) * 25 + fk];
      Wbf[(size_t)(1024 + fk) * 1024 + g] = f2bf(s);
    }
    if (i < 7168){   // zero pad rows fk=25..31
      int fk = 25 + (i >> 10), g = i & 1023;
      Wbf[(size_t)(1024 + fk) * 1024 + g] = 0;
    }
  } else {
    __shared__ float red2[6400];   // [256][25]
    __shared__ float red3[200];
    float pacc[25];
    #pragma unroll
    for (int fk = 0; fk < 25; fk++) pacc[fk] = 0.f;
    #pragma unroll
    for (int dt = 0; dt < 4; dt++){
      int e = tid * 4 + dt;
      float bde = bd[e];
      #pragma unroll
      for (int fk = 0; fk < 25; fk++){
        int f = fk / 5, k = fk - 5 * f;
        pacc[fk] += bde * Wa[f * 5120 + e * 5 + k];
      }
    }
    #pragma unroll
    for (int fk = 0; fk < 25; fk++) red2[tid * 25 + fk] = pacc[fk];
    __syncthreads();
    float s8 = 0.f;
    if (tid < 200){
      int fk = tid >> 3, c8 = tid & 7;
      for (int j = 0; j < 32; j++) s8 += red2[(c8 * 32 + j) * 25 + fk];
    }
    __syncthreads();
    if (tid < 200) red3[tid] = s8;
    __syncthreads();
    if (tid < 25){
      float s = 0.f;
      #pragma unroll
      for (int c8 = 0; c8 < 8; c8++) s += red3[tid * 8 + c8];
      cpart[tid] = s;
    }
    if (tid >= 224 && tid < 249){
      int fk = tid - 224, f = fk / 5, k = fk - 5 * f;
      float s = 0.f;
      for (int i2 = 0; i2 < 32; i2++) s += Wa[f * 5120 + i2 * 165 + k];
      eyepart[fk] = s;
    }
  }
}

// ---------------- K1: h = X*W^T + bias (bn<8) AND part = X*V (bn==8) ----------------
__global__ __launch_bounds__(256) void k_gemm(const unsigned short* __restrict__ A,   // [16384][1024] bf16
                                              const unsigned short* __restrict__ Bw,  // [1152][1024] bf16
                                              const float* __restrict__ bias,
                                              unsigned short* __restrict__ H,         // [B*2052][1024] bf16
                                              float* __restrict__ part){              // [16384][25] fp32
  __shared__ unsigned short sA[128 * 32];
  __shared__ unsigned short sB[128 * 32];
  const int tid = threadIdx.x;
  const int w = tid >> 6, l = tid & 63;
  const int bn = blockIdx.x, bm = blockIdx.y;    // bn fastest: 9 blocks share A tile
  const int M0 = bm * 128, N0 = bn * 128;
  const int wm = (w >> 1) * 64, wn = (w & 1) * 64;
  const int lm = l & 15, lk = l >> 4;
  f32x4 acc[4][4] = {};

  for (int kk = 0; kk < 1024; kk += 32){
    #pragma unroll
    for (int t = 0; t < 2; t++){
      int c = t * 256 + tid;
      const unsigned short* ga = A  + (size_t)(M0 + (c >> 2)) * 1024 + (kk + ((c & 3) << 3));
      __builtin_amdgcn_global_load_lds((const __attribute__((address_space(1))) void*)ga,
                                       (__attribute__((address_space(3))) void*)&sA[(t * 256 + w * 64) * 8],
                                       16, 0, 0);
      const unsigned short* gb = Bw + (size_t)(N0 + (c >> 2)) * 1024 + (kk + ((c & 3) << 3));
      __builtin_amdgcn_global_load_lds((const __attribute__((address_space(1))) void*)gb,
                                       (__attribute__((address_space(3))) void*)&sB[(t * 256 + w * 64) * 8],
                                       16, 0, 0);
    }
    __syncthreads();
    s16x8 aF[4], bF[4];
    #pragma unroll
    for (int m = 0; m < 4; m++) aF[m] = *(const s16x8*)&sA[(wm + m * 16 + lm) * 32 + lk * 8];
    #pragma unroll
    for (int n = 0; n < 4; n++) bF[n] = *(const s16x8*)&sB[(wn + n * 16 + lm) * 32 + lk * 8];
    #pragma unroll
    for (int m = 0; m < 4; m++){
      #pragma unroll
      for (int n = 0; n < 4; n++){
        acc[m][n] = __builtin_amdgcn_mfma_f32_16x16x32_bf16(aF[m], bF[n], acc[m][n], 0, 0, 0);
      }
    }
    __syncthreads();
  }

  if (bn < 8){
    float bv[4];
    #pragma unroll
    for (int n = 0; n < 4; n++) bv[n] = bias[N0 + wn + n * 16 + lm];
    #pragma unroll
    for (int m = 0; m < 4; m++){
      #pragma unroll
      for (int r = 0; r < 4; r++){
        int gm = M0 + wm + m * 16 + lk * 4 + r;
        int bb = gm >> 11, li = gm & 2047;
        unsigned short* orow = H + ((size_t)(bb * LPAD + 2 + li) << 10);
        #pragma unroll
        for (int n = 0; n < 4; n++){
          orow[N0 + wn + n * 16 + lm] = f2bf(acc[m][n][r] + bv[n]);
        }
      }
    }
  } else {
    if (wn == 0){
      #pragma unroll
      for (int m = 0; m < 4; m++){
        #pragma unroll
        for (int r = 0; r < 4; r++){
          int gm = M0 + wm + m * 16 + lk * 4 + r;
          float* prow = part + (size_t)gm * 25;
          #pragma unroll
          for (int n = 0; n < 2; n++){
            int fk = n * 16 + lm;
            if (fk < 25) prow[fk] = acc[m][n][r];
          }
        }
      }
    }
  }
}

// ---------------- K3: scores -> leaky_relu -> softmax -> s = prod(alpha) ----------------
__global__ void k_alpha(const float* __restrict__ part, const float* __restrict__ battn,
                        const float* __restrict__ cpart, const float* __restrict__ eyepart,
                        float* __restrict__ sprod){
  int t = blockIdx.x * 256 + threadIdx.x;
  if (t >= 16384) return;
  int bb = t >> 11, li = t & 2047;
  float sc[5];
  #pragma unroll
  for (int f = 0; f < 5; f++){
    float a = battn[f];
    #pragma unroll
    for (int k = 0; k < 5; k++){
      int q = li + k;
      int fk = f * 5 + k;
      if (q >= 2 && q < 2050)
        a += part[((size_t)(bb << 11) + (q - 2)) * 25 + fk] + cpart[fk];
      else
        a += eyepart[fk];
    }
    sc[f] = (a > 0.f) ? a : 0.01f * a;
  }
  float m = sc[0];
  #pragma unroll
  for (int f = 1; f < 5; f++) m = fmaxf(m, sc[f]);
  float e0 = expf(sc[0] - m), e1 = expf(sc[1] - m), e2 = expf(sc[2] - m),
        e3 = expf(sc[3] - m), e4 = expf(sc[4] - m);
  float ssum = e0 + e1 + e2 + e3 + e4;
  float inv = 1.f / ssum;
  float inv2 = inv * inv;
  sprod[t] = (e0 * e1 * e2 * e3 * e4) * inv2 * inv2 * inv;
}

// ---------------- K4: per-position 32x32 matrix chain (MFMA), scaled by s ----------------
__global__ __launch_bounds__(256) void k_chain(const unsigned short* __restrict__ H,
                                               const float* __restrict__ sp,
                                               float* __restrict__ out){
  const int tid = threadIdx.x;
  const int w = tid >> 6, l = tid & 63;
  const int pos = blockIdx.x * 4 + w;
  const int bb = pos >> 11, li = pos & 2047;
  const unsigned short* hbase = H + ((size_t)(bb * LPAD + li) << 10);
  const int col = l & 31;
  const int kh = (l >> 5) << 3;   // 0 or 8

  // initial carried matrix M = h4, loaded directly as B-fragments (col-major access)
  const unsigned short* h4 = hbase + 4 * 1024;
  unsigned q0, q1, q2, q3, q4, q5, q6, q7;
  {
    #define LD2(kk) ((unsigned)h4[(kk) * 32 + col] | ((unsigned)h4[((kk) + 1) * 32 + col] << 16))
    q0 = LD2(kh + 0);  q1 = LD2(kh + 2);  q2 = LD2(kh + 4);  q3 = LD2(kh + 6);
    q4 = LD2(kh + 16); q5 = LD2(kh + 18); q6 = LD2(kh + 20); q7 = LD2(kh + 22);
    #undef LD2
  }
  union { unsigned u[4]; s16x8 v; } ub0, ub1;
  ub0.u[0] = q0; ub0.u[1] = q1; ub0.u[2] = q2; ub0.u[3] = q3;
  ub1.u[0] = q4; ub1.u[1] = q5; ub1.u[2] = q6; ub1.u[3] = q7;
  s16x8 Bf0 = ub0.v, Bf1 = ub1.v;

  f32x16 acc;
  #pragma unroll
  for (int st = 0; st < 4; st++){
    const int km = 3 - st;                       // M = h_km * M
    const unsigned short* hA = hbase + (km << 10);
    s16x8 A0 = *(const s16x8*)(hA + col * 32 + kh);
    s16x8 A1 = *(const s16x8*)(hA + col * 32 + kh + 16);
    f32x16 z = {0,0,0,0,0,0,0,0,0,0,0,0,0,0,0,0};
    acc = __builtin_amdgcn_mfma_f32_32x32x16_bf16(A0, Bf0, z,   0, 0, 0);
    acc = __builtin_amdgcn_mfma_f32_32x32x16_bf16(A1, Bf1, acc, 0, 0, 0);
    if (st < 3){
      unsigned d0 = cvt_pk_bf16(acc[0],  acc[1]);
      unsigned d1 = cvt_pk_bf16(acc[2],  acc[3]);
      unsigned d2 = cvt_pk_bf16(acc[4],  acc[5]);
      unsigned d3 = cvt_pk_bf16(acc[6],  acc[7]);
      unsigned d4 = cvt_pk_bf16(acc[8],  acc[9]);
      unsigned d5 = cvt_pk_bf16(acc[10], acc[11]);
      unsigned d6 = cvt_pk_bf16(acc[12], acc[13]);
      unsigned d7 = cvt_pk_bf16(acc[14], acc[15]);
      unsigned p0 = __shfl_xor(d0, 32, 64);
      unsigned p1 = __shfl_xor(d1, 32, 64);
      unsigned p2 = __shfl_xor(d2, 32, 64);
      unsigned p3 = __shfl_xor(d3, 32, 64);
      unsigned p4 = __shfl_xor(d4, 32, 64);
      unsigned p5 = __shfl_xor(d5, 32, 64);
      unsigned p6 = __shfl_xor(d6, 32, 64);
      unsigned p7 = __shfl_xor(d7, 32, 64);
      const bool lo = (l < 32);
      ub0.u[0] = lo ? d0 : p2;  ub0.u[1] = lo ? d1 : p3;
      ub0.u[2] = lo ? p0 : d2;  ub0.u[3] = lo ? p1 : d3;
      ub1.u[0] = lo ? d4 : p6;  ub1.u[1] = lo ? d5 : p7;
      ub1.u[2] = lo ? p4 : d6;  ub1.u[3] = lo ? p5 : d7;
      Bf0 = ub0.v; Bf1 = ub1.v;
    }
  }

  const float sv = sp[pos];
  float* ob = out + ((size_t)pos << 10);
  #pragma unroll
  for (int t = 0; t < 16; t++){
    int row = (t & 3) + 8 * (t >> 2) + ((l >> 5) << 2);
    ob[row * 32 + col] = sv * acc[t];
  }
}

// ---------------- launcher ----------------
extern "C" void kernel_launch(void* const* d_in, const int* in_sizes, int n_in,
                              void* d_out, int out_size, void* d_ws, size_t ws_size,
                              hipStream_t stream){
  const float* X  = (const float*)d_in[0];   // [8][2048][32][32]
  const float* Wd = (const float*)d_in[1];   // [1024][1024]
  const float* bd = (const float*)d_in[2];   // [1024]
  const float* Wa = (const float*)d_in[3];   // [5][5120]
  const float* ba = (const float*)d_in[4];   // [5]
  float* out = (float*)d_out;

  char* ws = (char*)d_ws;
  unsigned short* Hpad = (unsigned short*)ws;                               // 33,619,968 B
  unsigned short* Wbf  = (unsigned short*)(ws + 33619968);                  // 1152*1024*2 = 2,359,296 B
  float*          sprod= (float*)(ws + 33619968 + 2359296);                 // 65,536 B
  float*          cpart= (float*)(ws + 33619968 + 2359296 + 65536);         // 128 B
  float*          eyep = (float*)(ws + 33619968 + 2359296 + 65536 + 128);   // 128 B
  // scratch parked in d_out (64 MiB fp32 output, fully rewritten by k_chain):
  unsigned short* Xbf  = (unsigned short*)d_out;                            // [0, 33.5MB)
  float*          part = (float*)((char*)d_out + 33554432);                 // [33.5MB, 35.2MB)
  float*          Vpart= (float*)((char*)d_out + 35192832);                 // [35.2MB, 36.0MB)

  k_cvt<<<16384, 256, 0, stream>>>(X, Xbf, 4194304);
  k_cvt<<<1024, 256, 0, stream>>>(Wd, Wbf, 262144);
  k_eye<<<128, 256, 0, stream>>>(Hpad);
  dim3 gf(32, 8);
  k_fuseW1<<<gf, 256, 0, stream>>>(Wd, Wa, Vpart);
  k_fuseW2<<<101, 256, 0, stream>>>(Vpart, Wa, bd, Wbf, cpart, eyep);
  dim3 g1(9, 128);
  k_gemm<<<g1, 256, 0, stream>>>(Xbf, Wbf, bd, Hpad, part);
  k_alpha<<<64, 256, 0, stream>>>(part, ba, cpart, eyep, sprod);
  k_chain<<<4096, 256, 0, stream>>>(Hpad, sprod, out);
}

// Round 4
// 132.636 us; speedup vs baseline: 1.6234x; 1.0653x over previous
//
#include <hip/hip_runtime.h>
#include <stdint.h>

typedef float  f32x4  __attribute__((ext_vector_type(4)));
typedef float  f32x16 __attribute__((ext_vector_type(16)));
typedef short  s16x8  __attribute__((ext_vector_type(8)));
typedef unsigned short u16x4 __attribute__((ext_vector_type(4)));

#define LPAD 2052   // L + 4 padded positions per batch row

__device__ __forceinline__ float bf2f(unsigned short u){
  unsigned v = ((unsigned)u) << 16;
  return __builtin_bit_cast(float, v);
}
__device__ __forceinline__ unsigned short f2bf(float f){
  unsigned u = __builtin_bit_cast(unsigned, f);
  u += 0x7fffu + ((u >> 16) & 1u);
  return (unsigned short)(u >> 16);
}
__device__ __forceinline__ unsigned cvt_pk_bf16(float lo, float hi){
  unsigned r;
  asm volatile("v_cvt_pk_bf16_f32 %0, %1, %2" : "=v"(r) : "v"(lo), "v"(hi));
  return r;
}

// ---------------- K0: fp32 -> bf16 convert (vectorized) ----------------
__global__ void k_cvt(const float* __restrict__ src, unsigned short* __restrict__ dst, int n4){
  int i = blockIdx.x * 256 + threadIdx.x;
  if (i >= n4) return;
  f32x4 v = ((const f32x4*)src)[i];
  u16x4 o;
  o[0] = f2bf(v[0]); o[1] = f2bf(v[1]); o[2] = f2bf(v[2]); o[3] = f2bf(v[3]);
  ((u16x4*)dst)[i] = o;
}

// ---------------- K0b: write identity pad matrices ----------------
__global__ void k_eye(unsigned short* __restrict__ H){
  int t = blockIdx.x * 256 + threadIdx.x;       // B*4*1024 = 32768
  int b = t >> 12;
  int r = t & 4095;
  int which = r >> 10;                           // 0..3
  int ij = r & 1023;
  int p = (which < 2) ? which : (2048 + which);  // 0,1,2050,2051
  H[((size_t)(b * LPAD + p) << 10) + ij] = ((ij >> 5) == (ij & 31)) ? 0x3F80 : 0;
}

// ---------------- K_fuseW1: Vpart[ey][g][fk] = sum_{e in chunk ey} Wd[e][g]*Wa2[e][fk] ----------------
__global__ __launch_bounds__(256) void k_fuseW1(const float* __restrict__ Wd,
                                                const float* __restrict__ Wa,
                                                float* __restrict__ Vpart){   // [8][1024][25] fp32
  __shared__ float smem[6400];
  float* was2 = smem;
  const int tid = threadIdx.x;
  const int gx = blockIdx.x, ey = blockIdx.y;
  for (int i = tid; i < 3200; i += 256){
    int le = i / 25, fk = i - le * 25;
    int f = fk / 5, k = fk - 5 * f;
    was2[le * 26 + fk] = Wa[f * 5120 + (ey * 128 + le) * 5 + k];
  }
  __syncthreads();
  const int gl = tid & 31, ch = tid >> 5;
  const int g = gx * 32 + gl;
  float acc[25];
  #pragma unroll
  for (int fk = 0; fk < 25; fk++) acc[fk] = 0.f;
  for (int le = ch * 16; le < ch * 16 + 16; ++le){
    float wd = Wd[(size_t)(ey * 128 + le) * 1024 + g];
    #pragma unroll
    for (int fk = 0; fk < 25; fk++) acc[fk] += wd * was2[le * 26 + fk];
  }
  __syncthreads();
  float* red = smem;
  #pragma unroll
  for (int fk = 0; fk < 25; fk++) red[tid * 25 + fk] = acc[fk];
  __syncthreads();
  for (int i = tid; i < 800; i += 256){
    int g2 = i / 25, fk = i - g2 * 25;
    float s = 0.f;
    #pragma unroll
    for (int c = 0; c < 8; c++) s += red[(c * 32 + g2) * 25 + fk];
    Vpart[((size_t)ey * 1024 + gx * 32 + g2) * 25 + fk] = s;
  }
}

// ---------------- K_fuseW2: reduce Vpart -> bf16 B-rows 1024+fk; cpart; eyepart ----------------
__global__ __launch_bounds__(256) void k_fuseW2(const float* __restrict__ Vpart,
                                                const float* __restrict__ Wa,
                                                const float* __restrict__ bd,
                                                unsigned short* __restrict__ Wbf,
                                                float* __restrict__ cpart,
                                                float* __restrict__ eyepart){
  const int tid = threadIdx.x;
  const int b = blockIdx.x;
  if (b < 100){
    int i = b * 256 + tid;
    if (i < 25600){
      int g = i / 25, fk = i - g * 25;
      float s = 0.f;
      #pragma unroll
      for (int ey = 0; ey < 8; ey++) s += Vpart[((size_t)ey * 1024 + g) * 25 + fk];
      Wbf[(size_t)(1024 + fk) * 1024 + g] = f2bf(s);
    }
    if (i < 7168){
      int fk = 25 + (i >> 10), g = i & 1023;
      Wbf[(size_t)(1024 + fk) * 1024 + g] = 0;
    }
  } else {
    __shared__ float red2[6400];
    __shared__ float red3[200];
    float pacc[25];
    #pragma unroll
    for (int fk = 0; fk < 25; fk++) pacc[fk] = 0.f;
    #pragma unroll
    for (int dt = 0; dt < 4; dt++){
      int e = tid * 4 + dt;
      float bde = bd[e];
      #pragma unroll
      for (int fk = 0; fk < 25; fk++){
        int f = fk / 5, k = fk - 5 * f;
        pacc[fk] += bde * Wa[f * 5120 + e * 5 + k];
      }
    }
    #pragma unroll
    for (int fk = 0; fk < 25; fk++) red2[tid * 25 + fk] = pacc[fk];
    __syncthreads();
    float s8 = 0.f;
    if (tid < 200){
      int fk = tid >> 3, c8 = tid & 7;
      for (int j = 0; j < 32; j++) s8 += red2[(c8 * 32 + j) * 25 + fk];
    }
    __syncthreads();
    if (tid < 200) red3[tid] = s8;
    __syncthreads();
    if (tid < 25){
      float s = 0.f;
      #pragma unroll
      for (int c8 = 0; c8 < 8; c8++) s += red3[tid * 8 + c8];
      cpart[tid] = s;
    }
    if (tid >= 224 && tid < 249){
      int fk = tid - 224, f = fk / 5, k = fk - 5 * f;
      float s = 0.f;
      for (int i2 = 0; i2 < 32; i2++) s += Wa[f * 5120 + i2 * 165 + k];
      eyepart[fk] = s;
    }
  }
}

// ---------------- staging helper (global -> LDS direct, 16B/lane) ----------------
__device__ __forceinline__ void stage_tiles(const unsigned short* __restrict__ A,
                                            const unsigned short* __restrict__ Bw,
                                            unsigned short* sa, unsigned short* sb,
                                            int M0, int N0, int kk, int tid, int w){
  #pragma unroll
  for (int t = 0; t < 2; t++){
    int c = t * 256 + tid;
    const unsigned short* ga = A  + (size_t)(M0 + (c >> 2)) * 1024 + (kk + ((c & 3) << 3));
    __builtin_amdgcn_global_load_lds((const __attribute__((address_space(1))) void*)ga,
                                     (__attribute__((address_space(3))) void*)&sa[(t * 256 + w * 64) * 8],
                                     16, 0, 0);
    const unsigned short* gb = Bw + (size_t)(N0 + (c >> 2)) * 1024 + (kk + ((c & 3) << 3));
    __builtin_amdgcn_global_load_lds((const __attribute__((address_space(1))) void*)gb,
                                     (__attribute__((address_space(3))) void*)&sb[(t * 256 + w * 64) * 8],
                                     16, 0, 0);
  }
}

// ---------------- K1: h = X*W^T + bias (bn<8) AND part = X*V (bn==8) ----------------
// XCD-swizzled 1-D grid (1152 blocks): all 9 bn-blocks of a bm row land on one XCD.
// 2-phase double-buffered pipeline: STAGE(next) issued before compute(cur); single
// barrier per k-step drains vmcnt after MFMA (load latency hidden under compute).
__global__ __launch_bounds__(256) void k_gemm(const unsigned short* __restrict__ A,   // [16384][1024] bf16
                                              const unsigned short* __restrict__ Bw,  // [1152][1024] bf16
                                              const float* __restrict__ bias,
                                              unsigned short* __restrict__ H,         // [B*2052][1024] bf16
                                              float* __restrict__ part){              // [16384][25] fp32
  __shared__ unsigned short sA[2][128 * 32];
  __shared__ unsigned short sB[2][128 * 32];
  const int tid = threadIdx.x;
  const int w = tid >> 6, l = tid & 63;
  const int hb = blockIdx.x;                 // 0..1151
  const int xcd = hb & 7;
  const int slot = hb >> 3;                  // 0..143
  const int bm = xcd * 16 + slot / 9;        // 0..127
  const int bn = slot % 9;                   // 0..8
  const int M0 = bm * 128, N0 = bn * 128;
  const int wm = (w >> 1) * 64, wn = (w & 1) * 64;
  const int lm = l & 15, lk = l >> 4;
  f32x4 acc[4][4] = {};

  stage_tiles(A, Bw, sA[0], sB[0], M0, N0, 0, tid, w);
  __syncthreads();                            // drain prologue loads

  int cur = 0;
  for (int t = 0; t < 32; ++t){
    if (t < 31)
      stage_tiles(A, Bw, sA[cur ^ 1], sB[cur ^ 1], M0, N0, (t + 1) * 32, tid, w);
    const unsigned short* sa = sA[cur];
    const unsigned short* sb = sB[cur];
    s16x8 aF[4], bF[4];
    #pragma unroll
    for (int m = 0; m < 4; m++) aF[m] = *(const s16x8*)&sa[(wm + m * 16 + lm) * 32 + lk * 8];
    #pragma unroll
    for (int n = 0; n < 4; n++) bF[n] = *(const s16x8*)&sb[(wn + n * 16 + lm) * 32 + lk * 8];
    #pragma unroll
    for (int m = 0; m < 4; m++){
      #pragma unroll
      for (int n = 0; n < 4; n++){
        acc[m][n] = __builtin_amdgcn_mfma_f32_16x16x32_bf16(aF[m], bF[n], acc[m][n], 0, 0, 0);
      }
    }
    __syncthreads();                          // drains vmcnt(0): next tile ready; protects cur for overwrite
    cur ^= 1;
  }

  if (bn < 8){
    float bv[4];
    #pragma unroll
    for (int n = 0; n < 4; n++) bv[n] = bias[N0 + wn + n * 16 + lm];
    #pragma unroll
    for (int m = 0; m < 4; m++){
      #pragma unroll
      for (int r = 0; r < 4; r++){
        int gm = M0 + wm + m * 16 + lk * 4 + r;
        int bb = gm >> 11, li = gm & 2047;
        unsigned short* orow = H + ((size_t)(bb * LPAD + 2 + li) << 10);
        #pragma unroll
        for (int n = 0; n < 4; n++){
          orow[N0 + wn + n * 16 + lm] = f2bf(acc[m][n][r] + bv[n]);
        }
      }
    }
  } else {
    if (wn == 0){
      #pragma unroll
      for (int m = 0; m < 4; m++){
        #pragma unroll
        for (int r = 0; r < 4; r++){
          int gm = M0 + wm + m * 16 + lk * 4 + r;
          float* prow = part + (size_t)gm * 25;
          #pragma unroll
          for (int n = 0; n < 2; n++){
            int fk = n * 16 + lm;
            if (fk < 25) prow[fk] = acc[m][n][r];
          }
        }
      }
    }
  }
}

// ---------------- K3: scores -> leaky_relu -> softmax -> s = prod(alpha) ----------------
__global__ void k_alpha(const float* __restrict__ part, const float* __restrict__ battn,
                        const float* __restrict__ cpart, const float* __restrict__ eyepart,
                        float* __restrict__ sprod){
  int t = blockIdx.x * 256 + threadIdx.x;
  if (t >= 16384) return;
  int bb = t >> 11, li = t & 2047;
  float sc[5];
  #pragma unroll
  for (int f = 0; f < 5; f++){
    float a = battn[f];
    #pragma unroll
    for (int k = 0; k < 5; k++){
      int q = li + k;
      int fk = f * 5 + k;
      if (q >= 2 && q < 2050)
        a += part[((size_t)(bb << 11) + (q - 2)) * 25 + fk] + cpart[fk];
      else
        a += eyepart[fk];
    }
    sc[f] = (a > 0.f) ? a : 0.01f * a;
  }
  float m = sc[0];
  #pragma unroll
  for (int f = 1; f < 5; f++) m = fmaxf(m, sc[f]);
  float e0 = expf(sc[0] - m), e1 = expf(sc[1] - m), e2 = expf(sc[2] - m),
        e3 = expf(sc[3] - m), e4 = expf(sc[4] - m);
  float ssum = e0 + e1 + e2 + e3 + e4;
  float inv = 1.f / ssum;
  float inv2 = inv * inv;
  sprod[t] = (e0 * e1 * e2 * e3 * e4) * inv2 * inv2 * inv;
}

// ---------------- K4: per-position 32x32 matrix chain (MFMA), scaled by s ----------------
// XCD-chunked block swizzle: each XCD owns one batch row -> sliding-window H reuse stays in its L2.
__global__ __launch_bounds__(256) void k_chain(const unsigned short* __restrict__ H,
                                               const float* __restrict__ sp,
                                               float* __restrict__ out){
  const int tid = threadIdx.x;
  const int w = tid >> 6, l = tid & 63;
  const int blk = (blockIdx.x & 7) * 512 + (blockIdx.x >> 3);   // bijective, 4096 blocks
  const int pos = blk * 4 + w;
  const int bb = pos >> 11, li = pos & 2047;
  const unsigned short* hbase = H + ((size_t)(bb * LPAD + li) << 10);
  const int col = l & 31;
  const int kh = (l >> 5) << 3;   // 0 or 8

  const unsigned short* h4 = hbase + 4 * 1024;
  unsigned q0, q1, q2, q3, q4, q5, q6, q7;
  {
    #define LD2(kk) ((unsigned)h4[(kk) * 32 + col] | ((unsigned)h4[((kk) + 1) * 32 + col] << 16))
    q0 = LD2(kh + 0);  q1 = LD2(kh + 2);  q2 = LD2(kh + 4);  q3 = LD2(kh + 6);
    q4 = LD2(kh + 16); q5 = LD2(kh + 18); q6 = LD2(kh + 20); q7 = LD2(kh + 22);
    #undef LD2
  }
  union { unsigned u[4]; s16x8 v; } ub0, ub1;
  ub0.u[0] = q0; ub0.u[1] = q1; ub0.u[2] = q2; ub0.u[3] = q3;
  ub1.u[0] = q4; ub1.u[1] = q5; ub1.u[2] = q6; ub1.u[3] = q7;
  s16x8 Bf0 = ub0.v, Bf1 = ub1.v;

  f32x16 acc;
  #pragma unroll
  for (int st = 0; st < 4; st++){
    const int km = 3 - st;                       // M = h_km * M
    const unsigned short* hA = hbase + (km << 10);
    s16x8 A0 = *(const s16x8*)(hA + col * 32 + kh);
    s16x8 A1 = *(const s16x8*)(hA + col * 32 + kh + 16);
    f32x16 z = {0,0,0,0,0,0,0,0,0,0,0,0,0,0,0,0};
    acc = __builtin_amdgcn_mfma_f32_32x32x16_bf16(A0, Bf0, z,   0, 0, 0);
    acc = __builtin_amdgcn_mfma_f32_32x32x16_bf16(A1, Bf1, acc, 0, 0, 0);
    if (st < 3){
      unsigned d0 = cvt_pk_bf16(acc[0],  acc[1]);
      unsigned d1 = cvt_pk_bf16(acc[2],  acc[3]);
      unsigned d2 = cvt_pk_bf16(acc[4],  acc[5]);
      unsigned d3 = cvt_pk_bf16(acc[6],  acc[7]);
      unsigned d4 = cvt_pk_bf16(acc[8],  acc[9]);
      unsigned d5 = cvt_pk_bf16(acc[10], acc[11]);
      unsigned d6 = cvt_pk_bf16(acc[12], acc[13]);
      unsigned d7 = cvt_pk_bf16(acc[14], acc[15]);
      unsigned p0 = __shfl_xor(d0, 32, 64);
      unsigned p1 = __shfl_xor(d1, 32, 64);
      unsigned p2 = __shfl_xor(d2, 32, 64);
      unsigned p3 = __shfl_xor(d3, 32, 64);
      unsigned p4 = __shfl_xor(d4, 32, 64);
      unsigned p5 = __shfl_xor(d5, 32, 64);
      unsigned p6 = __shfl_xor(d6, 32, 64);
      unsigned p7 = __shfl_xor(d7, 32, 64);
      const bool lo = (l < 32);
      ub0.u[0] = lo ? d0 : p2;  ub0.u[1] = lo ? d1 : p3;
      ub0.u[2] = lo ? p0 : d2;  ub0.u[3] = lo ? p1 : d3;
      ub1.u[0] = lo ? d4 : p6;  ub1.u[1] = lo ? d5 : p7;
      ub1.u[2] = lo ? p4 : d6;  ub1.u[3] = lo ? p5 : d7;
      Bf0 = ub0.v; Bf1 = ub1.v;
    }
  }

  const float sv = sp[pos];
  float* ob = out + ((size_t)pos << 10);
  #pragma unroll
  for (int t = 0; t < 16; t++){
    int row = (t & 3) + 8 * (t >> 2) + ((l >> 5) << 2);
    ob[row * 32 + col] = sv * acc[t];
  }
}

// ---------------- launcher ----------------
extern "C" void kernel_launch(void* const* d_in, const int* in_sizes, int n_in,
                              void* d_out, int out_size, void* d_ws, size_t ws_size,
                              hipStream_t stream){
  const float* X  = (const float*)d_in[0];   // [8][2048][32][32]
  const float* Wd = (const float*)d_in[1];   // [1024][1024]
  const float* bd = (const float*)d_in[2];   // [1024]
  const float* Wa = (const float*)d_in[3];   // [5][5120]
  const float* ba = (const float*)d_in[4];   // [5]
  float* out = (float*)d_out;

  char* ws = (char*)d_ws;
  unsigned short* Hpad = (unsigned short*)ws;                               // 33,619,968 B
  unsigned short* Wbf  = (unsigned short*)(ws + 33619968);                  // 1152*1024*2 = 2,359,296 B
  float*          sprod= (float*)(ws + 33619968 + 2359296);                 // 65,536 B
  float*          cpart= (float*)(ws + 33619968 + 2359296 + 65536);         // 128 B
  float*          eyep = (float*)(ws + 33619968 + 2359296 + 65536 + 128);   // 128 B
  // scratch parked in d_out (64 MiB fp32 output, fully rewritten by k_chain):
  unsigned short* Xbf  = (unsigned short*)d_out;                            // [0, 33.5MB)
  float*          part = (float*)((char*)d_out + 33554432);                 // [33.5MB, 35.2MB)
  float*          Vpart= (float*)((char*)d_out + 35192832);                 // [35.2MB, 36.0MB)

  k_cvt<<<16384, 256, 0, stream>>>(X, Xbf, 4194304);
  k_cvt<<<1024, 256, 0, stream>>>(Wd, Wbf, 262144);
  k_eye<<<128, 256, 0, stream>>>(Hpad);
  dim3 gf(32, 8);
  k_fuseW1<<<gf, 256, 0, stream>>>(Wd, Wa, Vpart);
  k_fuseW2<<<101, 256, 0, stream>>>(Vpart, Wa, bd, Wbf, cpart, eyep);
  k_gemm<<<1152, 256, 0, stream>>>(Xbf, Wbf, bd, Hpad, part);
  k_alpha<<<64, 256, 0, stream>>>(part, ba, cpart, eyep, sprod);
  k_chain<<<4096, 256, 0, stream>>>(Hpad, sprod, out);
}

// Round 5
// 125.470 us; speedup vs baseline: 1.7161x; 1.0571x over previous
//
#include <hip/hip_runtime.h>
#include <stdint.h>

typedef float  f32x4  __attribute__((ext_vector_type(4)));
typedef float  f32x16 __attribute__((ext_vector_type(16)));
typedef short  s16x8  __attribute__((ext_vector_type(8)));
typedef unsigned short u16x4 __attribute__((ext_vector_type(4)));

#define LPAD 2052   // L + 4 padded positions per batch row

__device__ __forceinline__ float bf2f(unsigned short u){
  unsigned v = ((unsigned)u) << 16;
  return __builtin_bit_cast(float, v);
}
__device__ __forceinline__ unsigned short f2bf(float f){
  unsigned u = __builtin_bit_cast(unsigned, f);
  u += 0x7fffu + ((u >> 16) & 1u);
  return (unsigned short)(u >> 16);
}
__device__ __forceinline__ unsigned cvt_pk_bf16(float lo, float hi){
  unsigned r;
  asm volatile("v_cvt_pk_bf16_f32 %0, %1, %2" : "=v"(r) : "v"(lo), "v"(hi));
  return r;
}

// ---------------- K0: fp32 -> bf16 convert (vectorized) ----------------
__global__ void k_cvt(const float* __restrict__ src, unsigned short* __restrict__ dst, int n4){
  int i = blockIdx.x * 256 + threadIdx.x;
  if (i >= n4) return;
  f32x4 v = ((const f32x4*)src)[i];
  u16x4 o;
  o[0] = f2bf(v[0]); o[1] = f2bf(v[1]); o[2] = f2bf(v[2]); o[3] = f2bf(v[3]);
  ((u16x4*)dst)[i] = o;
}

// ---------------- K0b: write identity pad matrices ----------------
__global__ void k_eye(unsigned short* __restrict__ H){
  int t = blockIdx.x * 256 + threadIdx.x;       // B*4*1024 = 32768
  int b = t >> 12;
  int r = t & 4095;
  int which = r >> 10;                           // 0..3
  int ij = r & 1023;
  int p = (which < 2) ? which : (2048 + which);  // 0,1,2050,2051
  H[((size_t)(b * LPAD + p) << 10) + ij] = ((ij >> 5) == (ij & 31)) ? 0x3F80 : 0;
}

// ---------------- K_fuseW1: Vpart[ey][g][fk] = sum_{e in chunk ey} Wd[e][g]*Wa2[e][fk] ----------------
__global__ __launch_bounds__(256) void k_fuseW1(const float* __restrict__ Wd,
                                                const float* __restrict__ Wa,
                                                float* __restrict__ Vpart){   // [8][1024][25] fp32
  __shared__ float smem[6400];
  float* was2 = smem;
  const int tid = threadIdx.x;
  const int gx = blockIdx.x, ey = blockIdx.y;
  for (int i = tid; i < 3200; i += 256){
    int le = i / 25, fk = i - le * 25;
    int f = fk / 5, k = fk - 5 * f;
    was2[le * 26 + fk] = Wa[f * 5120 + (ey * 128 + le) * 5 + k];
  }
  __syncthreads();
  const int gl = tid & 31, ch = tid >> 5;
  const int g = gx * 32 + gl;
  float acc[25];
  #pragma unroll
  for (int fk = 0; fk < 25; fk++) acc[fk] = 0.f;
  for (int le = ch * 16; le < ch * 16 + 16; ++le){
    float wd = Wd[(size_t)(ey * 128 + le) * 1024 + g];
    #pragma unroll
    for (int fk = 0; fk < 25; fk++) acc[fk] += wd * was2[le * 26 + fk];
  }
  __syncthreads();
  float* red = smem;
  #pragma unroll
  for (int fk = 0; fk < 25; fk++) red[tid * 25 + fk] = acc[fk];
  __syncthreads();
  for (int i = tid; i < 800; i += 256){
    int g2 = i / 25, fk = i - g2 * 25;
    float s = 0.f;
    #pragma unroll
    for (int c = 0; c < 8; c++) s += red[(c * 32 + g2) * 25 + fk];
    Vpart[((size_t)ey * 1024 + gx * 32 + g2) * 25 + fk] = s;
  }
}

// ---------------- K_fuseW2: reduce Vpart -> bf16 B-rows 1024+fk; cpart; eyepart ----------------
__global__ __launch_bounds__(256) void k_fuseW2(const float* __restrict__ Vpart,
                                                const float* __restrict__ Wa,
                                                const float* __restrict__ bd,
                                                unsigned short* __restrict__ Wbf,
                                                float* __restrict__ cpart,
                                                float* __restrict__ eyepart){
  const int tid = threadIdx.x;
  const int b = blockIdx.x;
  if (b < 100){
    int i = b * 256 + tid;
    if (i < 25600){
      int g = i / 25, fk = i - g * 25;
      float s = 0.f;
      #pragma unroll
      for (int ey = 0; ey < 8; ey++) s += Vpart[((size_t)ey * 1024 + g) * 25 + fk];
      Wbf[(size_t)(1024 + fk) * 1024 + g] = f2bf(s);
    }
    if (i < 7168){
      int fk = 25 + (i >> 10), g = i & 1023;
      Wbf[(size_t)(1024 + fk) * 1024 + g] = 0;
    }
  } else {
    __shared__ float red2[6400];
    __shared__ float red3[200];
    float pacc[25];
    #pragma unroll
    for (int fk = 0; fk < 25; fk++) pacc[fk] = 0.f;
    #pragma unroll
    for (int dt = 0; dt < 4; dt++){
      int e = tid * 4 + dt;
      float bde = bd[e];
      #pragma unroll
      for (int fk = 0; fk < 25; fk++){
        int f = fk / 5, k = fk - 5 * f;
        pacc[fk] += bde * Wa[f * 5120 + e * 5 + k];
      }
    }
    #pragma unroll
    for (int fk = 0; fk < 25; fk++) red2[tid * 25 + fk] = pacc[fk];
    __syncthreads();
    float s8 = 0.f;
    if (tid < 200){
      int fk = tid >> 3, c8 = tid & 7;
      for (int j = 0; j < 32; j++) s8 += red2[(c8 * 32 + j) * 25 + fk];
    }
    __syncthreads();
    if (tid < 200) red3[tid] = s8;
    __syncthreads();
    if (tid < 25){
      float s = 0.f;
      #pragma unroll
      for (int c8 = 0; c8 < 8; c8++) s += red3[tid * 8 + c8];
      cpart[tid] = s;
    }
    if (tid >= 224 && tid < 249){
      int fk = tid - 224, f = fk / 5, k = fk - 5 * f;
      float s = 0.f;
      for (int i2 = 0; i2 < 32; i2++) s += Wa[f * 5120 + i2 * 165 + k];
      eyepart[fk] = s;
    }
  }
}

// ---------------- staging helper (global -> LDS direct, 16B/lane; 4 vmem ops/thread) ----------------
__device__ __forceinline__ void stage_tiles(const unsigned short* __restrict__ A,
                                            const unsigned short* __restrict__ Bw,
                                            unsigned short* sa, unsigned short* sb,
                                            int M0, int N0, int kk, int tid, int w){
  #pragma unroll
  for (int t = 0; t < 2; t++){
    int c = t * 256 + tid;
    const unsigned short* ga = A  + (size_t)(M0 + (c >> 2)) * 1024 + (kk + ((c & 3) << 3));
    __builtin_amdgcn_global_load_lds((const __attribute__((address_space(1))) void*)ga,
                                     (__attribute__((address_space(3))) void*)&sa[(t * 256 + w * 64) * 8],
                                     16, 0, 0);
    const unsigned short* gb = Bw + (size_t)(N0 + (c >> 2)) * 1024 + (kk + ((c & 3) << 3));
    __builtin_amdgcn_global_load_lds((const __attribute__((address_space(1))) void*)gb,
                                     (__attribute__((address_space(3))) void*)&sb[(t * 256 + w * 64) * 8],
                                     16, 0, 0);
  }
}

// ---------------- K1: h = X*W^T + bias (bn<8) AND part = X*V (bn==8) ----------------
// XCD-swizzled 1-D grid (1152 blocks). 3-buffer pipeline, prefetch depth 2:
// per k-step: s_waitcnt vmcnt(4) (tile t landed, tile t+1 still in flight) ->
// s_barrier -> issue stage(t+2) -> ds_read+MFMA(t). vmcnt never drains to 0
// in the main loop; ~2 k-steps (>1000 cyc) cover the ~600 cyc L3 latency.
__global__ __launch_bounds__(256) void k_gemm(const unsigned short* __restrict__ A,   // [16384][1024] bf16
                                              const unsigned short* __restrict__ Bw,  // [1152][1024] bf16
                                              const float* __restrict__ bias,
                                              unsigned short* __restrict__ H,         // [B*2052][1024] bf16
                                              float* __restrict__ part){              // [16384][25] fp32
  __shared__ unsigned short sA[3][128 * 32];
  __shared__ unsigned short sB[3][128 * 32];
  const int tid = threadIdx.x;
  const int w = tid >> 6, l = tid & 63;
  const int hb = blockIdx.x;                 // 0..1151
  const int xcd = hb & 7;
  const int slot = hb >> 3;                  // 0..143
  const int bm = xcd * 16 + slot / 9;        // 0..127
  const int bn = slot % 9;                   // 0..8
  const int M0 = bm * 128, N0 = bn * 128;
  const int wm = (w >> 1) * 64, wn = (w & 1) * 64;
  const int lm = l & 15, lk = l >> 4;
  f32x4 acc[4][4] = {};

  stage_tiles(A, Bw, sA[0], sB[0], M0, N0, 0, tid, w);
  __builtin_amdgcn_sched_barrier(0);         // keep stage0 ops oldest in vmcnt order
  stage_tiles(A, Bw, sA[1], sB[1], M0, N0, 32, tid, w);
  __builtin_amdgcn_sched_barrier(0);

  int cur = 0;
  for (int t = 0; t < 31; ++t){
    asm volatile("s_waitcnt vmcnt(4)" ::: "memory");   // tile t's 4 loads retired
    __builtin_amdgcn_s_barrier();                      // tile t visible to all waves;
    __builtin_amdgcn_sched_barrier(0);                 // nothing moves above this point
    if (t < 30){
      int pf = cur + 2; if (pf >= 3) pf -= 3;
      stage_tiles(A, Bw, sA[pf], sB[pf], M0, N0, (t + 2) * 32, tid, w);
    }
    __builtin_amdgcn_sched_barrier(0);
    const unsigned short* sa = sA[cur];
    const unsigned short* sb = sB[cur];
    s16x8 aF[4], bF[4];
    #pragma unroll
    for (int m = 0; m < 4; m++) aF[m] = *(const s16x8*)&sa[(wm + m * 16 + lm) * 32 + lk * 8];
    #pragma unroll
    for (int n = 0; n < 4; n++) bF[n] = *(const s16x8*)&sb[(wn + n * 16 + lm) * 32 + lk * 8];
    #pragma unroll
    for (int m = 0; m < 4; m++){
      #pragma unroll
      for (int n = 0; n < 4; n++){
        acc[m][n] = __builtin_amdgcn_mfma_f32_16x16x32_bf16(aF[m], bF[n], acc[m][n], 0, 0, 0);
      }
    }
    cur = (cur == 2) ? 0 : cur + 1;
  }
  // last k-step (t=31): only its 4 loads remain in flight
  asm volatile("s_waitcnt vmcnt(0)" ::: "memory");
  __builtin_amdgcn_s_barrier();
  __builtin_amdgcn_sched_barrier(0);
  {
    const unsigned short* sa = sA[cur];
    const unsigned short* sb = sB[cur];
    s16x8 aF[4], bF[4];
    #pragma unroll
    for (int m = 0; m < 4; m++) aF[m] = *(const s16x8*)&sa[(wm + m * 16 + lm) * 32 + lk * 8];
    #pragma unroll
    for (int n = 0; n < 4; n++) bF[n] = *(const s16x8*)&sb[(wn + n * 16 + lm) * 32 + lk * 8];
    #pragma unroll
    for (int m = 0; m < 4; m++){
      #pragma unroll
      for (int n = 0; n < 4; n++){
        acc[m][n] = __builtin_amdgcn_mfma_f32_16x16x32_bf16(aF[m], bF[n], acc[m][n], 0, 0, 0);
      }
    }
  }

  if (bn < 8){
    float bv[4];
    #pragma unroll
    for (int n = 0; n < 4; n++) bv[n] = bias[N0 + wn + n * 16 + lm];
    #pragma unroll
    for (int m = 0; m < 4; m++){
      #pragma unroll
      for (int r = 0; r < 4; r++){
        int gm = M0 + wm + m * 16 + lk * 4 + r;
        int bb = gm >> 11, li = gm & 2047;
        unsigned short* orow = H + ((size_t)(bb * LPAD + 2 + li) << 10);
        #pragma unroll
        for (int n = 0; n < 4; n++){
          orow[N0 + wn + n * 16 + lm] = f2bf(acc[m][n][r] + bv[n]);
        }
      }
    }
  } else {
    if (wn == 0){
      #pragma unroll
      for (int m = 0; m < 4; m++){
        #pragma unroll
        for (int r = 0; r < 4; r++){
          int gm = M0 + wm + m * 16 + lk * 4 + r;
          float* prow = part + (size_t)gm * 25;
          #pragma unroll
          for (int n = 0; n < 2; n++){
            int fk = n * 16 + lm;
            if (fk < 25) prow[fk] = acc[m][n][r];
          }
        }
      }
    }
  }
}

// ---------------- K3: scores -> leaky_relu -> softmax -> s = prod(alpha) ----------------
__global__ void k_alpha(const float* __restrict__ part, const float* __restrict__ battn,
                        const float* __restrict__ cpart, const float* __restrict__ eyepart,
                        float* __restrict__ sprod){
  int t = blockIdx.x * 256 + threadIdx.x;
  if (t >= 16384) return;
  int bb = t >> 11, li = t & 2047;
  float sc[5];
  #pragma unroll
  for (int f = 0; f < 5; f++){
    float a = battn[f];
    #pragma unroll
    for (int k = 0; k < 5; k++){
      int q = li + k;
      int fk = f * 5 + k;
      if (q >= 2 && q < 2050)
        a += part[((size_t)(bb << 11) + (q - 2)) * 25 + fk] + cpart[fk];
      else
        a += eyepart[fk];
    }
    sc[f] = (a > 0.f) ? a : 0.01f * a;
  }
  float m = sc[0];
  #pragma unroll
  for (int f = 1; f < 5; f++) m = fmaxf(m, sc[f]);
  float e0 = expf(sc[0] - m), e1 = expf(sc[1] - m), e2 = expf(sc[2] - m),
        e3 = expf(sc[3] - m), e4 = expf(sc[4] - m);
  float ssum = e0 + e1 + e2 + e3 + e4;
  float inv = 1.f / ssum;
  float inv2 = inv * inv;
  sprod[t] = (e0 * e1 * e2 * e3 * e4) * inv2 * inv2 * inv;
}

// ---------------- K4: per-position 32x32 matrix chain (MFMA), scaled by s ----------------
__global__ __launch_bounds__(256) void k_chain(const unsigned short* __restrict__ H,
                                               const float* __restrict__ sp,
                                               float* __restrict__ out){
  const int tid = threadIdx.x;
  const int w = tid >> 6, l = tid & 63;
  const int blk = (blockIdx.x & 7) * 512 + (blockIdx.x >> 3);   // bijective, 4096 blocks
  const int pos = blk * 4 + w;
  const int bb = pos >> 11, li = pos & 2047;
  const unsigned short* hbase = H + ((size_t)(bb * LPAD + li) << 10);
  const int col = l & 31;
  const int kh = (l >> 5) << 3;   // 0 or 8

  const unsigned short* h4 = hbase + 4 * 1024;
  unsigned q0, q1, q2, q3, q4, q5, q6, q7;
  {
    #define LD2(kk) ((unsigned)h4[(kk) * 32 + col] | ((unsigned)h4[((kk) + 1) * 32 + col] << 16))
    q0 = LD2(kh + 0);  q1 = LD2(kh + 2);  q2 = LD2(kh + 4);  q3 = LD2(kh + 6);
    q4 = LD2(kh + 16); q5 = LD2(kh + 18); q6 = LD2(kh + 20); q7 = LD2(kh + 22);
    #undef LD2
  }
  union { unsigned u[4]; s16x8 v; } ub0, ub1;
  ub0.u[0] = q0; ub0.u[1] = q1; ub0.u[2] = q2; ub0.u[3] = q3;
  ub1.u[0] = q4; ub1.u[1] = q5; ub1.u[2] = q6; ub1.u[3] = q7;
  s16x8 Bf0 = ub0.v, Bf1 = ub1.v;

  f32x16 acc;
  #pragma unroll
  for (int st = 0; st < 4; st++){
    const int km = 3 - st;                       // M = h_km * M
    const unsigned short* hA = hbase + (km << 10);
    s16x8 A0 = *(const s16x8*)(hA + col * 32 + kh);
    s16x8 A1 = *(const s16x8*)(hA + col * 32 + kh + 16);
    f32x16 z = {0,0,0,0,0,0,0,0,0,0,0,0,0,0,0,0};
    acc = __builtin_amdgcn_mfma_f32_32x32x16_bf16(A0, Bf0, z,   0, 0, 0);
    acc = __builtin_amdgcn_mfma_f32_32x32x16_bf16(A1, Bf1, acc, 0, 0, 0);
    if (st < 3){
      unsigned d0 = cvt_pk_bf16(acc[0],  acc[1]);
      unsigned d1 = cvt_pk_bf16(acc[2],  acc[3]);
      unsigned d2 = cvt_pk_bf16(acc[4],  acc[5]);
      unsigned d3 = cvt_pk_bf16(acc[6],  acc[7]);
      unsigned d4 = cvt_pk_bf16(acc[8],  acc[9]);
      unsigned d5 = cvt_pk_bf16(acc[10], acc[11]);
      unsigned d6 = cvt_pk_bf16(acc[12], acc[13]);
      unsigned d7 = cvt_pk_bf16(acc[14], acc[15]);
      unsigned p0 = __shfl_xor(d0, 32, 64);
      unsigned p1 = __shfl_xor(d1, 32, 64);
      unsigned p2 = __shfl_xor(d2, 32, 64);
      unsigned p3 = __shfl_xor(d3, 32, 64);
      unsigned p4 = __shfl_xor(d4, 32, 64);
      unsigned p5 = __shfl_xor(d5, 32, 64);
      unsigned p6 = __shfl_xor(d6, 32, 64);
      unsigned p7 = __shfl_xor(d7, 32, 64);
      const bool lo = (l < 32);
      ub0.u[0] = lo ? d0 : p2;  ub0.u[1] = lo ? d1 : p3;
      ub0.u[2] = lo ? p0 : d2;  ub0.u[3] = lo ? p1 : d3;
      ub1.u[0] = lo ? d4 : p6;  ub1.u[1] = lo ? d5 : p7;
      ub1.u[2] = lo ? p4 : d6;  ub1.u[3] = lo ? p5 : d7;
      Bf0 = ub0.v; Bf1 = ub1.v;
    }
  }

  const float sv = sp[pos];
  float* ob = out + ((size_t)pos << 10);
  #pragma unroll
  for (int t = 0; t < 16; t++){
    int row = (t & 3) + 8 * (t >> 2) + ((l >> 5) << 2);
    ob[row * 32 + col] = sv * acc[t];
  }
}

// ---------------- launcher ----------------
extern "C" void kernel_launch(void* const* d_in, const int* in_sizes, int n_in,
                              void* d_out, int out_size, void* d_ws, size_t ws_size,
                              hipStream_t stream){
  const float* X  = (const float*)d_in[0];   // [8][2048][32][32]
  const float* Wd = (const float*)d_in[1];   // [1024][1024]
  const float* bd = (const float*)d_in[2];   // [1024]
  const float* Wa = (const float*)d_in[3];   // [5][5120]
  const float* ba = (const float*)d_in[4];   // [5]
  float* out = (float*)d_out;

  char* ws = (char*)d_ws;
  unsigned short* Hpad = (unsigned short*)ws;                               // 33,619,968 B
  unsigned short* Wbf  = (unsigned short*)(ws + 33619968);                  // 1152*1024*2 = 2,359,296 B
  float*          sprod= (float*)(ws + 33619968 + 2359296);                 // 65,536 B
  float*          cpart= (float*)(ws + 33619968 + 2359296 + 65536);         // 128 B
  float*          eyep = (float*)(ws + 33619968 + 2359296 + 65536 + 128);   // 128 B
  // scratch parked in d_out (64 MiB fp32 output, fully rewritten by k_chain):
  unsigned short* Xbf  = (unsigned short*)d_out;                            // [0, 33.5MB)
  float*          part = (float*)((char*)d_out + 33554432);                 // [33.5MB, 35.2MB)
  float*          Vpart= (float*)((char*)d_out + 35192832);                 // [35.2MB, 36.0MB)

  k_cvt<<<16384, 256, 0, stream>>>(X, Xbf, 4194304);
  k_cvt<<<1024, 256, 0, stream>>>(Wd, Wbf, 262144);
  k_eye<<<128, 256, 0, stream>>>(Hpad);
  dim3 gf(32, 8);
  k_fuseW1<<<gf, 256, 0, stream>>>(Wd, Wa, Vpart);
  k_fuseW2<<<101, 256, 0, stream>>>(Vpart, Wa, bd, Wbf, cpart, eyep);
  k_gemm<<<1152, 256, 0, stream>>>(Xbf, Wbf, bd, Hpad, part);
  k_alpha<<<64, 256, 0, stream>>>(part, ba, cpart, eyep, sprod);
  k_chain<<<4096, 256, 0, stream>>>(Hpad, sprod, out);
}

// Round 6
// 124.320 us; speedup vs baseline: 1.7319x; 1.0092x over previous
//
#include <hip/hip_runtime.h>
#include <stdint.h>

typedef float  f32x4  __attribute__((ext_vector_type(4)));
typedef float  f32x16 __attribute__((ext_vector_type(16)));
typedef short  s16x8  __attribute__((ext_vector_type(8)));
typedef unsigned short u16x4 __attribute__((ext_vector_type(4)));

#define LPAD 2052   // L + 4 padded positions per batch row

__device__ __forceinline__ float bf2f(unsigned short u){
  unsigned v = ((unsigned)u) << 16;
  return __builtin_bit_cast(float, v);
}
__device__ __forceinline__ unsigned short f2bf(float f){
  unsigned u = __builtin_bit_cast(unsigned, f);
  u += 0x7fffu + ((u >> 16) & 1u);
  return (unsigned short)(u >> 16);
}
__device__ __forceinline__ unsigned cvt_pk_bf16(float lo, float hi){
  unsigned r;
  asm volatile("v_cvt_pk_bf16_f32 %0, %1, %2" : "=v"(r) : "v"(lo), "v"(hi));
  return r;
}

// ---------------- K0: fp32 -> bf16 convert (vectorized) ----------------
__global__ void k_cvt(const float* __restrict__ src, unsigned short* __restrict__ dst, int n4){
  int i = blockIdx.x * 256 + threadIdx.x;
  if (i >= n4) return;
  f32x4 v = ((const f32x4*)src)[i];
  u16x4 o;
  o[0] = f2bf(v[0]); o[1] = f2bf(v[1]); o[2] = f2bf(v[2]); o[3] = f2bf(v[3]);
  ((u16x4*)dst)[i] = o;
}

// ---------------- K0b: write identity pad matrices ----------------
__global__ void k_eye(unsigned short* __restrict__ H){
  int t = blockIdx.x * 256 + threadIdx.x;       // B*4*1024 = 32768
  int b = t >> 12;
  int r = t & 4095;
  int which = r >> 10;                           // 0..3
  int ij = r & 1023;
  int p = (which < 2) ? which : (2048 + which);  // 0,1,2050,2051
  H[((size_t)(b * LPAD + p) << 10) + ij] = ((ij >> 5) == (ij & 31)) ? 0x3F80 : 0;
}

// ---------------- K_fuseW1 ----------------
__global__ __launch_bounds__(256) void k_fuseW1(const float* __restrict__ Wd,
                                                const float* __restrict__ Wa,
                                                float* __restrict__ Vpart){   // [8][1024][25] fp32
  __shared__ float smem[6400];
  float* was2 = smem;
  const int tid = threadIdx.x;
  const int gx = blockIdx.x, ey = blockIdx.y;
  for (int i = tid; i < 3200; i += 256){
    int le = i / 25, fk = i - le * 25;
    int f = fk / 5, k = fk - 5 * f;
    was2[le * 26 + fk] = Wa[f * 5120 + (ey * 128 + le) * 5 + k];
  }
  __syncthreads();
  const int gl = tid & 31, ch = tid >> 5;
  const int g = gx * 32 + gl;
  float acc[25];
  #pragma unroll
  for (int fk = 0; fk < 25; fk++) acc[fk] = 0.f;
  for (int le = ch * 16; le < ch * 16 + 16; ++le){
    float wd = Wd[(size_t)(ey * 128 + le) * 1024 + g];
    #pragma unroll
    for (int fk = 0; fk < 25; fk++) acc[fk] += wd * was2[le * 26 + fk];
  }
  __syncthreads();
  float* red = smem;
  #pragma unroll
  for (int fk = 0; fk < 25; fk++) red[tid * 25 + fk] = acc[fk];
  __syncthreads();
  for (int i = tid; i < 800; i += 256){
    int g2 = i / 25, fk = i - g2 * 25;
    float s = 0.f;
    #pragma unroll
    for (int c = 0; c < 8; c++) s += red[(c * 32 + g2) * 25 + fk];
    Vpart[((size_t)ey * 1024 + gx * 32 + g2) * 25 + fk] = s;
  }
}

// ---------------- K_fuseW2 ----------------
__global__ __launch_bounds__(256) void k_fuseW2(const float* __restrict__ Vpart,
                                                const float* __restrict__ Wa,
                                                const float* __restrict__ bd,
                                                unsigned short* __restrict__ Wbf,
                                                float* __restrict__ cpart,
                                                float* __restrict__ eyepart){
  const int tid = threadIdx.x;
  const int b = blockIdx.x;
  if (b < 100){
    int i = b * 256 + tid;
    if (i < 25600){
      int g = i / 25, fk = i - g * 25;
      float s = 0.f;
      #pragma unroll
      for (int ey = 0; ey < 8; ey++) s += Vpart[((size_t)ey * 1024 + g) * 25 + fk];
      Wbf[(size_t)(1024 + fk) * 1024 + g] = f2bf(s);
    }
    if (i < 7168){
      int fk = 25 + (i >> 10), g = i & 1023;
      Wbf[(size_t)(1024 + fk) * 1024 + g] = 0;
    }
  } else {
    __shared__ float red2[6400];
    __shared__ float red3[200];
    float pacc[25];
    #pragma unroll
    for (int fk = 0; fk < 25; fk++) pacc[fk] = 0.f;
    #pragma unroll
    for (int dt = 0; dt < 4; dt++){
      int e = tid * 4 + dt;
      float bde = bd[e];
      #pragma unroll
      for (int fk = 0; fk < 25; fk++){
        int f = fk / 5, k = fk - 5 * f;
        pacc[fk] += bde * Wa[f * 5120 + e * 5 + k];
      }
    }
    #pragma unroll
    for (int fk = 0; fk < 25; fk++) red2[tid * 25 + fk] = pacc[fk];
    __syncthreads();
    float s8 = 0.f;
    if (tid < 200){
      int fk = tid >> 3, c8 = tid & 7;
      for (int j = 0; j < 32; j++) s8 += red2[(c8 * 32 + j) * 25 + fk];
    }
    __syncthreads();
    if (tid < 200) red3[tid] = s8;
    __syncthreads();
    if (tid < 25){
      float s = 0.f;
      #pragma unroll
      for (int c8 = 0; c8 < 8; c8++) s += red3[tid * 8 + c8];
      cpart[tid] = s;
    }
    if (tid >= 224 && tid < 249){
      int fk = tid - 224, f = fk / 5, k = fk - 5 * f;
      float s = 0.f;
      for (int i2 = 0; i2 < 32; i2++) s += Wa[f * 5120 + i2 * 165 + k];
      eyepart[fk] = s;
    }
  }
}

// ---------------- K1: 256x256 8-phase GEMM (T2+T3+T4+T5), part fused as 5th N-tile ----
#define MFMA16 __builtin_amdgcn_mfma_f32_16x16x32_bf16

__global__ __launch_bounds__(512, 2) void k_gemm8(const unsigned short* __restrict__ A,   // [16384][1024]
                                                  const unsigned short* __restrict__ Bw,  // [1280][1024]
                                                  const float* __restrict__ bias,
                                                  unsigned short* __restrict__ H,
                                                  float* __restrict__ part){
  __shared__ __align__(128) unsigned short lds[65536];  // 128 KB: [buf][A h0,A h1,B h0,B h1] x16KB
  const int tid = threadIdx.x;
  const int wid = tid >> 6, l = tid & 63;
  const int wm2 = wid >> 2, wn2 = wid & 3;
  const int lm = l & 15, lk = l >> 4;
  const int hb = blockIdx.x;                 // 0..319
  const int xcd = hb & 7, sl = hb >> 3;      // 0..39
  const int bm = xcd * 8 + sl / 5, bn = sl % 5;
  const int M0 = bm * 256, N0 = bn * 256;

  // swizzle st_16x32: stored = L ^ ((L>>9 &1)<<5); on reads collapses to per-lane const
  const unsigned swz = ((lm >> 2) & 1u) << 5;
  const unsigned ko0 = ((unsigned)lk * 16) ^ swz;
  const unsigned ko1 = 64u + (((unsigned)lk * 16) ^ swz);
  const unsigned aB0 = (unsigned)wm2 * 16384;
  const unsigned bB0 = 32768u + (unsigned)(wn2 >> 1) * 16384;
  const unsigned rB  = (((unsigned)(wn2 & 1)) * 64 + lm) * 128;  // + n*2048
  const unsigned rA  = (unsigned)lm * 128;                       // + m*2048

  f32x4 acc[8][4] = {};
  s16x8 af[4][2], bf0[2][2], bf1[2][2];

  // stage one 16KB half-tile (pre-swizzled source, linear LDS dest)
  #define STAGE_HALF(panelRow, mat, bufbase)                                         \
    { _Pragma("unroll")                                                              \
      for (int j = 0; j < 2; j++){                                                   \
        unsigned d = (unsigned)(j * 512 + tid) * 16;                                 \
        unsigned sw = d ^ (((d >> 9) & 1u) << 5);                                    \
        const unsigned short* g = (mat) + (size_t)((panelRow) + (sw >> 7)) * 1024    \
                                  + ktK + ((sw & 127) >> 1);                         \
        __builtin_amdgcn_global_load_lds(                                            \
          (const __attribute__((address_space(1))) void*)g,                          \
          (__attribute__((address_space(3))) void*)&lds[((bufbase) + d) >> 1],       \
          16, 0, 0);                                                                 \
      } }
  #define STAGE_Q(b, kt, q)                                                          \
    { const int ktK = (kt) * 64;                                                     \
      if ((q) == 0)      STAGE_HALF(M0,       A,  (b)*65536u)                        \
      else if ((q) == 1) STAGE_HALF(M0+128,   A,  (b)*65536u+16384u)                 \
      else if ((q) == 2) STAGE_HALF(N0,       Bw, (b)*65536u+32768u)                 \
      else               STAGE_HALF(N0+128,   Bw, (b)*65536u+49152u) }

  #define RD_A(mh) { _Pragma("unroll")                                               \
    for (int m = 0; m < 4; m++){                                                     \
      af[m][0] = *(const s16x8*)&lds[(aB + rA + ((mh)*4+m)*2048u + ko0) >> 1];       \
      af[m][1] = *(const s16x8*)&lds[(aB + rA + ((mh)*4+m)*2048u + ko1) >> 1]; } }
  #define RD_B(dst, nh) { _Pragma("unroll")                                          \
    for (int n = 0; n < 2; n++){                                                     \
      dst[n][0] = *(const s16x8*)&lds[(bB + rB + ((nh)*2+n)*2048u + ko0) >> 1];      \
      dst[n][1] = *(const s16x8*)&lds[(bB + rB + ((nh)*2+n)*2048u + ko1) >> 1]; } }
  #define MM(mo, no, bfr) { _Pragma("unroll")                                        \
    for (int m = 0; m < 4; m++){ _Pragma("unroll")                                   \
      for (int n = 0; n < 2; n++){                                                   \
        acc[(mo)+m][(no)+n] = MFMA16(af[m][0], bfr[n][0], acc[(mo)+m][(no)+n], 0,0,0); \
        acc[(mo)+m][(no)+n] = MFMA16(af[m][1], bfr[n][1], acc[(mo)+m][(no)+n], 0,0,0); } } }
  #define BARA    { __builtin_amdgcn_s_barrier(); asm volatile("s_waitcnt lgkmcnt(0)":::"memory"); __builtin_amdgcn_sched_barrier(0); }
  #define BARA_NL { __builtin_amdgcn_s_barrier(); __builtin_amdgcn_sched_barrier(0); }
  #define BARB    { __builtin_amdgcn_s_barrier(); __builtin_amdgcn_sched_barrier(0); }

  // prologue: kt0 full (8 loads) + kt1.h0 (2 loads); wait kt0 -> vmcnt(2)
  STAGE_Q(0, 0, 0); STAGE_Q(0, 0, 1); STAGE_Q(0, 0, 2); STAGE_Q(0, 0, 3);
  __builtin_amdgcn_sched_barrier(0);
  STAGE_Q(1, 1, 0);
  __builtin_amdgcn_sched_barrier(0);
  asm volatile("s_waitcnt vmcnt(2)" ::: "memory");
  __builtin_amdgcn_s_barrier();
  __builtin_amdgcn_sched_barrier(0);

  #pragma unroll 1
  for (int i = 0; i < 8; i++){
    const int ktA = 2 * i + 1;     // buf1 tile completing (h1..h3 staged ph1-3)
    const int ktB = 2 * i + 2;     // next buf0 tile (ph4-7)
    const int ktC = 2 * i + 3;     // next buf1 h0 (ph8)
    unsigned aB = aB0, bB = bB0;   // buf0
    // ph1
    RD_A(0); RD_B(bf0, 0);
    STAGE_Q(1, ktA, 1);
    BARA; __builtin_amdgcn_s_setprio(1); MM(0, 0, bf0); __builtin_amdgcn_s_setprio(0); BARB;
    // ph2
    RD_B(bf1, 1);
    STAGE_Q(1, ktA, 2);
    BARA; __builtin_amdgcn_s_setprio(1); MM(0, 2, bf1); __builtin_amdgcn_s_setprio(0); BARB;
    // ph3
    RD_A(1);
    STAGE_Q(1, ktA, 3);
    BARA; __builtin_amdgcn_s_setprio(1); MM(4, 2, bf1); __builtin_amdgcn_s_setprio(0); BARB;
    // ph4 (no reads)
    if (ktB < 16) STAGE_Q(0, ktB, 0);
    BARA_NL; __builtin_amdgcn_s_setprio(1); MM(4, 0, bf0); __builtin_amdgcn_s_setprio(0);
    if (i == 7) { asm volatile("s_waitcnt vmcnt(0)" ::: "memory"); }
    else        { asm volatile("s_waitcnt vmcnt(2)" ::: "memory"); }
    BARB;
    // ph5-8 on buf1
    aB = 65536u + aB0; bB = 65536u + bB0;
    RD_A(0); RD_B(bf0, 0);
    if (ktB < 16) STAGE_Q(0, ktB, 1);
    BARA; __builtin_amdgcn_s_setprio(1); MM(0, 0, bf0); __builtin_amdgcn_s_setprio(0); BARB;
    RD_B(bf1, 1);
    if (ktB < 16) STAGE_Q(0, ktB, 2);
    BARA; __builtin_amdgcn_s_setprio(1); MM(0, 2, bf1); __builtin_amdgcn_s_setprio(0); BARB;
    RD_A(1);
    if (ktB < 16) STAGE_Q(0, ktB, 3);
    BARA; __builtin_amdgcn_s_setprio(1); MM(4, 2, bf1); __builtin_amdgcn_s_setprio(0); BARB;
    if (ktC < 16) STAGE_Q(1, ktC, 0);
    BARA_NL; __builtin_amdgcn_s_setprio(1); MM(4, 0, bf0); __builtin_amdgcn_s_setprio(0);
    if (i < 7) { asm volatile("s_waitcnt vmcnt(2)" ::: "memory"); }
    BARB;
  }

  // epilogue
  if (bn < 4){
    float bv[4];
    #pragma unroll
    for (int n = 0; n < 4; n++) bv[n] = bias[N0 + wn2 * 64 + n * 16 + lm];
    #pragma unroll
    for (int m = 0; m < 8; m++){
      #pragma unroll
      for (int r = 0; r < 4; r++){
        int gm = M0 + wm2 * 128 + m * 16 + lk * 4 + r;
        int bb = gm >> 11, li = gm & 2047;
        unsigned short* orow = H + ((size_t)(bb * LPAD + 2 + li) << 10);
        #pragma unroll
        for (int n = 0; n < 4; n++){
          orow[N0 + wn2 * 64 + n * 16 + lm] = f2bf(acc[m][n][r] + bv[n]);
        }
      }
    }
  } else if (wn2 == 0){
    #pragma unroll
    for (int m = 0; m < 8; m++){
      #pragma unroll
      for (int r = 0; r < 4; r++){
        int gm = M0 + wm2 * 128 + m * 16 + lk * 4 + r;
        float* prow = part + (size_t)gm * 25;
        #pragma unroll
        for (int n = 0; n < 2; n++){
          int fk = n * 16 + lm;
          if (fk < 25) prow[fk] = acc[m][n][r];
        }
      }
    }
  }
  #undef STAGE_HALF
  #undef STAGE_Q
  #undef RD_A
  #undef RD_B
  #undef MM
  #undef BARA
  #undef BARA_NL
  #undef BARB
}

// ---------------- K3: scores -> leaky_relu -> softmax -> s = prod(alpha) ----------------
__global__ void k_alpha(const float* __restrict__ part, const float* __restrict__ battn,
                        const float* __restrict__ cpart, const float* __restrict__ eyepart,
                        float* __restrict__ sprod){
  int t = blockIdx.x * 256 + threadIdx.x;
  if (t >= 16384) return;
  int bb = t >> 11, li = t & 2047;
  float sc[5];
  #pragma unroll
  for (int f = 0; f < 5; f++){
    float a = battn[f];
    #pragma unroll
    for (int k = 0; k < 5; k++){
      int q = li + k;
      int fk = f * 5 + k;
      if (q >= 2 && q < 2050)
        a += part[((size_t)(bb << 11) + (q - 2)) * 25 + fk] + cpart[fk];
      else
        a += eyepart[fk];
    }
    sc[f] = (a > 0.f) ? a : 0.01f * a;
  }
  float m = sc[0];
  #pragma unroll
  for (int f = 1; f < 5; f++) m = fmaxf(m, sc[f]);
  float e0 = expf(sc[0] - m), e1 = expf(sc[1] - m), e2 = expf(sc[2] - m),
        e3 = expf(sc[3] - m), e4 = expf(sc[4] - m);
  float ssum = e0 + e1 + e2 + e3 + e4;
  float inv = 1.f / ssum;
  float inv2 = inv * inv;
  sprod[t] = (e0 * e1 * e2 * e3 * e4) * inv2 * inv2 * inv;
}

// ---------------- K4: per-position 32x32 matrix chain (MFMA), scaled by s ----------------
__global__ __launch_bounds__(256) void k_chain(const unsigned short* __restrict__ H,
                                               const float* __restrict__ sp,
                                               float* __restrict__ out){
  const int tid = threadIdx.x;
  const int w = tid >> 6, l = tid & 63;
  const int blk = (blockIdx.x & 7) * 512 + (blockIdx.x >> 3);
  const int pos = blk * 4 + w;
  const int bb = pos >> 11, li = pos & 2047;
  const unsigned short* hbase = H + ((size_t)(bb * LPAD + li) << 10);
  const int col = l & 31;
  const int kh = (l >> 5) << 3;

  const unsigned short* h4 = hbase + 4 * 1024;
  unsigned q0, q1, q2, q3, q4, q5, q6, q7;
  {
    #define LD2(kk) ((unsigned)h4[(kk) * 32 + col] | ((unsigned)h4[((kk) + 1) * 32 + col] << 16))
    q0 = LD2(kh + 0);  q1 = LD2(kh + 2);  q2 = LD2(kh + 4);  q3 = LD2(kh + 6);
    q4 = LD2(kh + 16); q5 = LD2(kh + 18); q6 = LD2(kh + 20); q7 = LD2(kh + 22);
    #undef LD2
  }
  union { unsigned u[4]; s16x8 v; } ub0, ub1;
  ub0.u[0] = q0; ub0.u[1] = q1; ub0.u[2] = q2; ub0.u[3] = q3;
  ub1.u[0] = q4; ub1.u[1] = q5; ub1.u[2] = q6; ub1.u[3] = q7;
  s16x8 Bf0 = ub0.v, Bf1 = ub1.v;

  f32x16 acc;
  #pragma unroll
  for (int st = 0; st < 4; st++){
    const int km = 3 - st;
    const unsigned short* hA = hbase + (km << 10);
    s16x8 A0 = *(const s16x8*)(hA + col * 32 + kh);
    s16x8 A1 = *(const s16x8*)(hA + col * 32 + kh + 16);
    f32x16 z = {0,0,0,0,0,0,0,0,0,0,0,0,0,0,0,0};
    acc = __builtin_amdgcn_mfma_f32_32x32x16_bf16(A0, Bf0, z,   0, 0, 0);
    acc = __builtin_amdgcn_mfma_f32_32x32x16_bf16(A1, Bf1, acc, 0, 0, 0);
    if (st < 3){
      unsigned d0 = cvt_pk_bf16(acc[0],  acc[1]);
      unsigned d1 = cvt_pk_bf16(acc[2],  acc[3]);
      unsigned d2 = cvt_pk_bf16(acc[4],  acc[5]);
      unsigned d3 = cvt_pk_bf16(acc[6],  acc[7]);
      unsigned d4 = cvt_pk_bf16(acc[8],  acc[9]);
      unsigned d5 = cvt_pk_bf16(acc[10], acc[11]);
      unsigned d6 = cvt_pk_bf16(acc[12], acc[13]);
      unsigned d7 = cvt_pk_bf16(acc[14], acc[15]);
      unsigned p0 = __shfl_xor(d0, 32, 64);
      unsigned p1 = __shfl_xor(d1, 32, 64);
      unsigned p2 = __shfl_xor(d2, 32, 64);
      unsigned p3 = __shfl_xor(d3, 32, 64);
      unsigned p4 = __shfl_xor(d4, 32, 64);
      unsigned p5 = __shfl_xor(d5, 32, 64);
      unsigned p6 = __shfl_xor(d6, 32, 64);
      unsigned p7 = __shfl_xor(d7, 32, 64);
      const bool lo = (l < 32);
      ub0.u[0] = lo ? d0 : p2;  ub0.u[1] = lo ? d1 : p3;
      ub0.u[2] = lo ? p0 : d2;  ub0.u[3] = lo ? p1 : d3;
      ub1.u[0] = lo ? d4 : p6;  ub1.u[1] = lo ? d5 : p7;
      ub1.u[2] = lo ? p4 : d6;  ub1.u[3] = lo ? p5 : d7;
      Bf0 = ub0.v; Bf1 = ub1.v;
    }
  }

  const float sv = sp[pos];
  float* ob = out + ((size_t)pos << 10);
  #pragma unroll
  for (int t = 0; t < 16; t++){
    int row = (t & 3) + 8 * (t >> 2) + ((l >> 5) << 2);
    ob[row * 32 + col] = sv * acc[t];
  }
}

// ---------------- launcher ----------------
extern "C" void kernel_launch(void* const* d_in, const int* in_sizes, int n_in,
                              void* d_out, int out_size, void* d_ws, size_t ws_size,
                              hipStream_t stream){
  const float* X  = (const float*)d_in[0];
  const float* Wd = (const float*)d_in[1];
  const float* bd = (const float*)d_in[2];
  const float* Wa = (const float*)d_in[3];
  const float* ba = (const float*)d_in[4];
  float* out = (float*)d_out;

  char* ws = (char*)d_ws;
  unsigned short* Hpad = (unsigned short*)ws;                               // 33,619,968 B
  unsigned short* Wbf  = (unsigned short*)(ws + 33619968);                  // 1280*1024*2 = 2,621,440 B
  float*          sprod= (float*)(ws + 33619968 + 2621440);                 // 65,536 B
  float*          cpart= (float*)(ws + 33619968 + 2621440 + 65536);         // 128 B
  float*          eyep = (float*)(ws + 33619968 + 2621440 + 65536 + 128);   // 128 B
  // scratch parked in d_out (fully rewritten by k_chain):
  unsigned short* Xbf  = (unsigned short*)d_out;                            // [0, 33.5MB)
  float*          part = (float*)((char*)d_out + 33554432);                 // [33.5MB, 35.2MB)
  float*          Vpart= (float*)((char*)d_out + 35192832);                 // [35.2MB, 36.0MB)

  k_cvt<<<16384, 256, 0, stream>>>(X, Xbf, 4194304);
  k_cvt<<<1024, 256, 0, stream>>>(Wd, Wbf, 262144);
  k_eye<<<128, 256, 0, stream>>>(Hpad);
  dim3 gf(32, 8);
  k_fuseW1<<<gf, 256, 0, stream>>>(Wd, Wa, Vpart);
  k_fuseW2<<<101, 256, 0, stream>>>(Vpart, Wa, bd, Wbf, cpart, eyep);
  k_gemm8<<<320, 512, 0, stream>>>(Xbf, Wbf, bd, Hpad, part);
  k_alpha<<<64, 256, 0, stream>>>(part, ba, cpart, eyep, sprod);
  k_chain<<<4096, 256, 0, stream>>>(Hpad, sprod, out);
}

// Round 7
// 97.483 us; speedup vs baseline: 2.2088x; 1.2753x over previous
//
#include <hip/hip_runtime.h>
#include <stdint.h>

typedef float  f32x4  __attribute__((ext_vector_type(4)));
typedef float  f32x16 __attribute__((ext_vector_type(16)));
typedef short  s16x8  __attribute__((ext_vector_type(8)));
typedef unsigned short u16x4 __attribute__((ext_vector_type(4)));

#define LPAD 2052   // L + 4 padded positions per batch row

__device__ __forceinline__ float bf2f(unsigned short u){
  unsigned v = ((unsigned)u) << 16;
  return __builtin_bit_cast(float, v);
}
__device__ __forceinline__ unsigned short f2bf(float f){
  unsigned u = __builtin_bit_cast(unsigned, f);
  u += 0x7fffu + ((u >> 16) & 1u);
  return (unsigned short)(u >> 16);
}
__device__ __forceinline__ unsigned cvt_pk_bf16(float lo, float hi){
  unsigned r;
  asm volatile("v_cvt_pk_bf16_f32 %0, %1, %2" : "=v"(r) : "v"(lo), "v"(hi));
  return r;
}

// ---------------- K0: fp32 -> bf16 convert (vectorized) ----------------
__global__ void k_cvt(const float* __restrict__ src, unsigned short* __restrict__ dst, int n4){
  int i = blockIdx.x * 256 + threadIdx.x;
  if (i >= n4) return;
  f32x4 v = ((const f32x4*)src)[i];
  u16x4 o;
  o[0] = f2bf(v[0]); o[1] = f2bf(v[1]); o[2] = f2bf(v[2]); o[3] = f2bf(v[3]);
  ((u16x4*)dst)[i] = o;
}

// ---------------- K0b: write identity pad matrices ----------------
__global__ void k_eye(unsigned short* __restrict__ H){
  int t = blockIdx.x * 256 + threadIdx.x;       // B*4*1024 = 32768
  int b = t >> 12;
  int r = t & 4095;
  int which = r >> 10;                           // 0..3
  int ij = r & 1023;
  int p = (which < 2) ? which : (2048 + which);  // 0,1,2050,2051
  H[((size_t)(b * LPAD + p) << 10) + ij] = ((ij >> 5) == (ij & 31)) ? 0x3F80 : 0;
}

// ---------------- K_wprep: Wa2g[col][k] = bf16(Wa[f][k*5+kk]), col=f*5+kk<25 else 0 ----
__global__ void k_wprep(const float* __restrict__ Wa, unsigned short* __restrict__ Wa2g){
  int t = blockIdx.x * 256 + threadIdx.x;       // 32768 = 32*1024
  int col = t >> 10, k = t & 1023;
  int f = col / 5, kk = col - 5 * f;
  unsigned short v = 0;
  if (col < 25) v = f2bf(Wa[f * 5120 + k * 5 + kk]);
  Wa2g[t] = v;
}

// ---------------- K1: 256x256 8-phase GEMM (grid=256, 1 block/CU, row&7 swizzle) ----
#define MFMA16 __builtin_amdgcn_mfma_f32_16x16x32_bf16

__global__ __launch_bounds__(512, 2) void k_gemm8(const unsigned short* __restrict__ A,   // [16384][1024]
                                                  const unsigned short* __restrict__ Bw,  // [1024][1024]
                                                  const float* __restrict__ bias,
                                                  unsigned short* __restrict__ H){
  __shared__ __align__(128) unsigned short lds[65536];  // 128 KB
  const int tid = threadIdx.x;
  const int wid = tid >> 6, l = tid & 63;
  const int wm2 = wid >> 2, wn2 = wid & 3;
  const int lm = l & 15, lk = l >> 4;
  const int hb = blockIdx.x;                 // 0..255
  const int xcd = hb & 7, sl = hb >> 3;      // 0..31
  const int bm = xcd * 8 + (sl >> 2), bn = sl & 3;
  const int M0 = bm * 256, N0 = bn * 256;

  // swizzle: element chunk c (16B) of row stored at chunk c ^ (row&7)
  const unsigned ko0 = (unsigned)((lk ^ (lm & 7)) << 4);
  const unsigned ko1 = ko0 ^ 64u;
  const unsigned aB0 = (unsigned)wm2 * 16384;
  const unsigned bB0 = 32768u + (unsigned)(wn2 >> 1) * 16384;
  const unsigned rB  = (((unsigned)(wn2 & 1)) * 64 + lm) * 128;  // + n*2048
  const unsigned rA  = (unsigned)lm * 128;                       // + m*2048

  f32x4 acc[8][4] = {};
  s16x8 af[4][2], bf0[2][2], bf1[2][2];

  // stage one 16KB half-tile: linear LDS dest, inverse-swizzled global source
  #define STAGE_HALF(panelRow, mat, bufbase)                                         \
    { _Pragma("unroll")                                                              \
      for (int j = 0; j < 2; j++){                                                   \
        unsigned d = (unsigned)(j * 512 + tid) * 16;                                 \
        unsigned row = d >> 7;                                                       \
        unsigned srcC = ((d >> 4) & 7u) ^ (row & 7u);                                \
        const unsigned short* g = (mat) + (size_t)((panelRow) + row) * 1024          \
                                  + ktK + srcC * 8;                                  \
        __builtin_amdgcn_global_load_lds(                                            \
          (const __attribute__((address_space(1))) void*)g,                          \
          (__attribute__((address_space(3))) void*)&lds[((bufbase) + d) >> 1],       \
          16, 0, 0);                                                                 \
      } }
  #define STAGE_Q(b, kt, q)                                                          \
    { const int ktK = (kt) * 64;                                                     \
      if ((q) == 0)      STAGE_HALF(M0,       A,  (b)*65536u)                        \
      else if ((q) == 1) STAGE_HALF(M0+128,   A,  (b)*65536u+16384u)                 \
      else if ((q) == 2) STAGE_HALF(N0,       Bw, (b)*65536u+32768u)                 \
      else               STAGE_HALF(N0+128,   Bw, (b)*65536u+49152u) }

  #define RD_A(mh) { _Pragma("unroll")                                               \
    for (int m = 0; m < 4; m++){                                                     \
      af[m][0] = *(const s16x8*)&lds[(aB + rA + ((mh)*4+m)*2048u + ko0) >> 1];       \
      af[m][1] = *(const s16x8*)&lds[(aB + rA + ((mh)*4+m)*2048u + ko1) >> 1]; } }
  #define RD_B(dst, nh) { _Pragma("unroll")                                          \
    for (int n = 0; n < 2; n++){                                                     \
      dst[n][0] = *(const s16x8*)&lds[(bB + rB + ((nh)*2+n)*2048u + ko0) >> 1];      \
      dst[n][1] = *(const s16x8*)&lds[(bB + rB + ((nh)*2+n)*2048u + ko1) >> 1]; } }
  #define MM(mo, no, bfr) { _Pragma("unroll")                                        \
    for (int m = 0; m < 4; m++){ _Pragma("unroll")                                   \
      for (int n = 0; n < 2; n++){                                                   \
        acc[(mo)+m][(no)+n] = MFMA16(af[m][0], bfr[n][0], acc[(mo)+m][(no)+n], 0,0,0); \
        acc[(mo)+m][(no)+n] = MFMA16(af[m][1], bfr[n][1], acc[(mo)+m][(no)+n], 0,0,0); } } }
  #define BARA    { __builtin_amdgcn_s_barrier(); asm volatile("s_waitcnt lgkmcnt(0)":::"memory"); __builtin_amdgcn_sched_barrier(0); }
  #define BARA_NL { __builtin_amdgcn_s_barrier(); __builtin_amdgcn_sched_barrier(0); }
  #define BARB    { __builtin_amdgcn_s_barrier(); __builtin_amdgcn_sched_barrier(0); }

  // prologue: kt0 full (8 loads) + kt1.h0 (2 loads); wait kt0 -> vmcnt(2)
  STAGE_Q(0, 0, 0); STAGE_Q(0, 0, 1); STAGE_Q(0, 0, 2); STAGE_Q(0, 0, 3);
  __builtin_amdgcn_sched_barrier(0);
  STAGE_Q(1, 1, 0);
  __builtin_amdgcn_sched_barrier(0);
  asm volatile("s_waitcnt vmcnt(2)" ::: "memory");
  __builtin_amdgcn_s_barrier();
  __builtin_amdgcn_sched_barrier(0);

  #pragma unroll 1
  for (int i = 0; i < 8; i++){
    const int ktA = 2 * i + 1;
    const int ktB = 2 * i + 2;
    const int ktC = 2 * i + 3;
    unsigned aB = aB0, bB = bB0;   // buf0
    // ph1
    RD_A(0); RD_B(bf0, 0);
    STAGE_Q(1, ktA, 1);
    BARA; __builtin_amdgcn_s_setprio(1); MM(0, 0, bf0); __builtin_amdgcn_s_setprio(0); BARB;
    // ph2
    RD_B(bf1, 1);
    STAGE_Q(1, ktA, 2);
    BARA; __builtin_amdgcn_s_setprio(1); MM(0, 2, bf1); __builtin_amdgcn_s_setprio(0); BARB;
    // ph3
    RD_A(1);
    STAGE_Q(1, ktA, 3);
    BARA; __builtin_amdgcn_s_setprio(1); MM(4, 2, bf1); __builtin_amdgcn_s_setprio(0); BARB;
    // ph4
    if (ktB < 16) STAGE_Q(0, ktB, 0);
    BARA_NL; __builtin_amdgcn_s_setprio(1); MM(4, 0, bf0); __builtin_amdgcn_s_setprio(0);
    if (i == 7) { asm volatile("s_waitcnt vmcnt(0)" ::: "memory"); }
    else        { asm volatile("s_waitcnt vmcnt(2)" ::: "memory"); }
    BARB;
    // ph5-8 on buf1
    aB = 65536u + aB0; bB = 65536u + bB0;
    RD_A(0); RD_B(bf0, 0);
    if (ktB < 16) STAGE_Q(0, ktB, 1);
    BARA; __builtin_amdgcn_s_setprio(1); MM(0, 0, bf0); __builtin_amdgcn_s_setprio(0); BARB;
    RD_B(bf1, 1);
    if (ktB < 16) STAGE_Q(0, ktB, 2);
    BARA; __builtin_amdgcn_s_setprio(1); MM(0, 2, bf1); __builtin_amdgcn_s_setprio(0); BARB;
    RD_A(1);
    if (ktB < 16) STAGE_Q(0, ktB, 3);
    BARA; __builtin_amdgcn_s_setprio(1); MM(4, 2, bf1); __builtin_amdgcn_s_setprio(0); BARB;
    if (ktC < 16) STAGE_Q(1, ktC, 0);
    BARA_NL; __builtin_amdgcn_s_setprio(1); MM(4, 0, bf0); __builtin_amdgcn_s_setprio(0);
    if (i < 7) { asm volatile("s_waitcnt vmcnt(2)" ::: "memory"); }
    BARB;
  }

  // epilogue: h = acc + bias -> bf16 H
  float bv[4];
  #pragma unroll
  for (int n = 0; n < 4; n++) bv[n] = bias[N0 + wn2 * 64 + n * 16 + lm];
  #pragma unroll
  for (int m = 0; m < 8; m++){
    #pragma unroll
    for (int r = 0; r < 4; r++){
      int gm = M0 + wm2 * 128 + m * 16 + lk * 4 + r;
      int bb = gm >> 11, li = gm & 2047;
      unsigned short* orow = H + ((size_t)(bb * LPAD + 2 + li) << 10);
      #pragma unroll
      for (int n = 0; n < 4; n++){
        orow[N0 + wn2 * 64 + n * 16 + lm] = f2bf(acc[m][n][r] + bv[n]);
      }
    }
  }
  #undef STAGE_HALF
  #undef STAGE_Q
  #undef RD_A
  #undef RD_B
  #undef MM
  #undef BARA
  #undef BARA_NL
  #undef BARB
}

// ---------------- K2: part[p][0..31] = <Hpad[p], Wa2g[col]>  (thin MFMA GEMM) ----------------
// B (64KB) staged once into swizzled LDS; A streamed global->reg; no inner barriers.
__global__ __launch_bounds__(256) void k_part(const unsigned short* __restrict__ H,    // [16416][1024]
                                              const unsigned short* __restrict__ Wa2g, // [32][1024]
                                              float* __restrict__ part){               // [16512][32]
  __shared__ unsigned short sB[32768];  // [32 col][1024 k], chunk c at c^(col&7)
  const int tid = threadIdx.x;
  const int wv = tid >> 6, l = tid & 63;
  const int lm = l & 15, lk = l >> 4;
  #pragma unroll
  for (int j = 0; j < 16; j++){
    unsigned d = (unsigned)(j * 256 + tid) * 16;     // byte 0..65535
    unsigned col = d >> 11;
    unsigned srcC = ((d >> 4) & 127u) ^ (col & 7u);
    const unsigned short* g = Wa2g + col * 1024 + srcC * 8;
    __builtin_amdgcn_global_load_lds((const __attribute__((address_space(1))) void*)g,
                                     (__attribute__((address_space(3))) void*)&sB[d >> 1],
                                     16, 0, 0);
  }
  __syncthreads();
  const int rbase = blockIdx.x * 128 + wv * 32;
  f32x4 acc[2][2] = {};
  for (int kk = 0; kk < 1024; kk += 32){
    s16x8 aF[2], bF[2];
    #pragma unroll
    for (int m = 0; m < 2; m++)
      aF[m] = *(const s16x8*)(H + (size_t)(rbase + m * 16 + lm) * 1024 + kk + lk * 8);
    #pragma unroll
    for (int n = 0; n < 2; n++){
      unsigned col = (unsigned)(n * 16 + lm);
      unsigned c = (unsigned)(kk >> 3) + (unsigned)lk;
      bF[n] = *(const s16x8*)&sB[(col * 2048u + ((c ^ (col & 7u)) << 4)) >> 1];
    }
    #pragma unroll
    for (int m = 0; m < 2; m++){
      #pragma unroll
      for (int n = 0; n < 2; n++)
        acc[m][n] = MFMA16(aF[m], bF[n], acc[m][n], 0, 0, 0);
    }
  }
  #pragma unroll
  for (int m = 0; m < 2; m++){
    #pragma unroll
    for (int r = 0; r < 4; r++){
      int row = rbase + m * 16 + lk * 4 + r;
      #pragma unroll
      for (int n = 0; n < 2; n++)
        part[(size_t)row * 32 + n * 16 + lm] = acc[m][n][r];
    }
  }
}

// ---------------- K3: scores -> leaky_relu -> softmax -> s = prod(alpha) ----------------
__global__ void k_alpha(const float* __restrict__ part, const float* __restrict__ battn,
                        float* __restrict__ sprod){
  int t = blockIdx.x * 256 + threadIdx.x;
  if (t >= 16384) return;
  int bb = t >> 11, li = t & 2047;
  int pbase = bb * LPAD + li;
  float sc[5];
  #pragma unroll
  for (int f = 0; f < 5; f++){
    float a = battn[f];
    #pragma unroll
    for (int k = 0; k < 5; k++)
      a += part[(size_t)(pbase + k) * 32 + f * 5 + k];
    sc[f] = (a > 0.f) ? a : 0.01f * a;
  }
  float m = sc[0];
  #pragma unroll
  for (int f = 1; f < 5; f++) m = fmaxf(m, sc[f]);
  float e0 = expf(sc[0] - m), e1 = expf(sc[1] - m), e2 = expf(sc[2] - m),
        e3 = expf(sc[3] - m), e4 = expf(sc[4] - m);
  float ssum = e0 + e1 + e2 + e3 + e4;
  float inv = 1.f / ssum;
  float inv2 = inv * inv;
  sprod[t] = (e0 * e1 * e2 * e3 * e4) * inv2 * inv2 * inv;
}

// ---------------- K4: per-position 32x32 matrix chain (MFMA), scaled by s ----------------
__global__ __launch_bounds__(256) void k_chain(const unsigned short* __restrict__ H,
                                               const float* __restrict__ sp,
                                               float* __restrict__ out){
  const int tid = threadIdx.x;
  const int w = tid >> 6, l = tid & 63;
  const int blk = (blockIdx.x & 7) * 512 + (blockIdx.x >> 3);
  const int pos = blk * 4 + w;
  const int bb = pos >> 11, li = pos & 2047;
  const unsigned short* hbase = H + ((size_t)(bb * LPAD + li) << 10);
  const int col = l & 31;
  const int kh = (l >> 5) << 3;

  const unsigned short* h4 = hbase + 4 * 1024;
  unsigned q0, q1, q2, q3, q4, q5, q6, q7;
  {
    #define LD2(kk) ((unsigned)h4[(kk) * 32 + col] | ((unsigned)h4[((kk) + 1) * 32 + col] << 16))
    q0 = LD2(kh + 0);  q1 = LD2(kh + 2);  q2 = LD2(kh + 4);  q3 = LD2(kh + 6);
    q4 = LD2(kh + 16); q5 = LD2(kh + 18); q6 = LD2(kh + 20); q7 = LD2(kh + 22);
    #undef LD2
  }
  union { unsigned u[4]; s16x8 v; } ub0, ub1;
  ub0.u[0] = q0; ub0.u[1] = q1; ub0.u[2] = q2; ub0.u[3] = q3;
  ub1.u[0] = q4; ub1.u[1] = q5; ub1.u[2] = q6; ub1.u[3] = q7;
  s16x8 Bf0 = ub0.v, Bf1 = ub1.v;

  f32x16 acc;
  #pragma unroll
  for (int st = 0; st < 4; st++){
    const int km = 3 - st;
    const unsigned short* hA = hbase + (km << 10);
    s16x8 A0 = *(const s16x8*)(hA + col * 32 + kh);
    s16x8 A1 = *(const s16x8*)(hA + col * 32 + kh + 16);
    f32x16 z = {0,0,0,0,0,0,0,0,0,0,0,0,0,0,0,0};
    acc = __builtin_amdgcn_mfma_f32_32x32x16_bf16(A0, Bf0, z,   0, 0, 0);
    acc = __builtin_amdgcn_mfma_f32_32x32x16_bf16(A1, Bf1, acc, 0, 0, 0);
    if (st < 3){
      unsigned d0 = cvt_pk_bf16(acc[0],  acc[1]);
      unsigned d1 = cvt_pk_bf16(acc[2],  acc[3]);
      unsigned d2 = cvt_pk_bf16(acc[4],  acc[5]);
      unsigned d3 = cvt_pk_bf16(acc[6],  acc[7]);
      unsigned d4 = cvt_pk_bf16(acc[8],  acc[9]);
      unsigned d5 = cvt_pk_bf16(acc[10], acc[11]);
      unsigned d6 = cvt_pk_bf16(acc[12], acc[13]);
      unsigned d7 = cvt_pk_bf16(acc[14], acc[15]);
      unsigned p0 = __shfl_xor(d0, 32, 64);
      unsigned p1 = __shfl_xor(d1, 32, 64);
      unsigned p2 = __shfl_xor(d2, 32, 64);
      unsigned p3 = __shfl_xor(d3, 32, 64);
      unsigned p4 = __shfl_xor(d4, 32, 64);
      unsigned p5 = __shfl_xor(d5, 32, 64);
      unsigned p6 = __shfl_xor(d6, 32, 64);
      unsigned p7 = __shfl_xor(d7, 32, 64);
      const bool lo = (l < 32);
      ub0.u[0] = lo ? d0 : p2;  ub0.u[1] = lo ? d1 : p3;
      ub0.u[2] = lo ? p0 : d2;  ub0.u[3] = lo ? p1 : d3;
      ub1.u[0] = lo ? d4 : p6;  ub1.u[1] = lo ? d5 : p7;
      ub1.u[2] = lo ? p4 : d6;  ub1.u[3] = lo ? p5 : d7;
      Bf0 = ub0.v; Bf1 = ub1.v;
    }
  }

  const float sv = sp[pos];
  float* ob = out + ((size_t)pos << 10);
  #pragma unroll
  for (int t = 0; t < 16; t++){
    int row = (t & 3) + 8 * (t >> 2) + ((l >> 5) << 2);
    ob[row * 32 + col] = sv * acc[t];
  }
}

// ---------------- launcher ----------------
extern "C" void kernel_launch(void* const* d_in, const int* in_sizes, int n_in,
                              void* d_out, int out_size, void* d_ws, size_t ws_size,
                              hipStream_t stream){
  const float* X  = (const float*)d_in[0];
  const float* Wd = (const float*)d_in[1];
  const float* bd = (const float*)d_in[2];
  const float* Wa = (const float*)d_in[3];
  const float* ba = (const float*)d_in[4];
  float* out = (float*)d_out;

  char* ws = (char*)d_ws;
  unsigned short* Hpad = (unsigned short*)ws;                               // 33,619,968 B
  unsigned short* Wbf  = (unsigned short*)(ws + 33619968);                  // 1024*1024*2 = 2,097,152 B
  float*          sprod= (float*)(ws + 33619968 + 2097152);                 // 65,536 B
  unsigned short* Wa2g = (unsigned short*)(ws + 33619968 + 2097152 + 65536);// 32*1024*2 = 65,536 B
  // scratch parked in d_out (fully rewritten by k_chain):
  unsigned short* Xbf  = (unsigned short*)d_out;                            // [0, 33,554,432)
  float*          part = (float*)((char*)d_out + 33554432);                 // 16512*32*4 = 2,113,536 B

  k_cvt<<<16384, 256, 0, stream>>>(X, Xbf, 4194304);
  k_cvt<<<1024, 256, 0, stream>>>(Wd, Wbf, 262144);
  k_eye<<<128, 256, 0, stream>>>(Hpad);
  k_wprep<<<128, 256, 0, stream>>>(Wa, Wa2g);
  k_gemm8<<<256, 512, 0, stream>>>(Xbf, Wbf, bd, Hpad);
  k_part<<<129, 256, 0, stream>>>(Hpad, Wa2g, part);
  k_alpha<<<64, 256, 0, stream>>>(part, ba, sprod);
  k_chain<<<4096, 256, 0, stream>>>(Hpad, sprod, out);
}